// Round 8
// baseline (2699.404 us; speedup 1.0000x reference)
//
#include <hip/hip_runtime.h>
#include <cmath>

#define S 4096
#define HID 768
#define NH 12
#define DH 64
#define CHUNK 256
#define NC (S / CHUNK)
#define NG 16
#define FF 3072
#define NLAYER 12
#define QKV3 (3 * HID)
#define NEGV -1e9f

typedef _Float16 f16;
typedef __attribute__((ext_vector_type(2))) _Float16 f16x2;
typedef __attribute__((ext_vector_type(4))) _Float16 f16x4;
typedef __attribute__((ext_vector_type(8))) _Float16 f16x8;
typedef __attribute__((ext_vector_type(4))) float f32x4;

__device__ __forceinline__ void async16(f16* lds, const f16* g) {
  __builtin_amdgcn_global_load_lds((const __attribute__((address_space(1))) unsigned int*)g,
                                   (__attribute__((address_space(3))) unsigned int*)lds,
                                   16, 0, 0);
}

// bijective XCD swizzle for nwg % 8 == 0
__device__ __forceinline__ int xcd_swz(int lin, int nwg) {
  return (lin & 7) * (nwg >> 3) + (lin >> 3);
}

__device__ __forceinline__ float block_reduce_sum(float v, float* red) {
  int t = threadIdx.x;
  red[t] = v; __syncthreads();
  for (int st = 128; st > 0; st >>= 1) {
    if (t < st) red[t] += red[t + st];
    __syncthreads();
  }
  float r = red[0]; __syncthreads();
  return r;
}

// ---------------- gidx / gvalid (matches jax top_k semantics) ----------------
__global__ void gidx_kernel(const int* __restrict__ gmask, int* __restrict__ gidx,
                            float* __restrict__ gvalid) {
  if (threadIdx.x != 0 || blockIdx.x != 0) return;
  int cnt = 0;
  for (int s = 0; s < S && cnt < NG; s++)
    if (gmask[s] > 0) { gidx[cnt] = s; gvalid[cnt] = 1.f; cnt++; }
  for (int s = 0; s < S && cnt < NG; s++)
    if (gmask[s] == 0) { gidx[cnt] = s; gvalid[cnt] = 0.f; cnt++; }
}

// ---------------- embedding + LayerNorm (writes f16 residual stream) ----------------
__global__ __launch_bounds__(256) void embed_ln_kernel(
    const int* __restrict__ ids, const float* __restrict__ tok,
    const float* __restrict__ pos, const float* __restrict__ g,
    const float* __restrict__ b, f16* __restrict__ h16) {
  int s = blockIdx.x, t = threadIdx.x;
  __shared__ float xs[HID];
  __shared__ float red[256];
  const float* tr = tok + (size_t)ids[s] * HID;
  const float* pr = pos + (size_t)s * HID;
  float ls = 0.f;
  for (int i = t; i < HID; i += 256) { float v = tr[i] + pr[i]; xs[i] = v; ls += v; }
  float mu = block_reduce_sum(ls, red) * (1.f / HID);
  float lv = 0.f;
  for (int i = t; i < HID; i += 256) { float d = xs[i] - mu; lv += d * d; }
  float var = block_reduce_sum(lv, red) * (1.f / HID);
  float inv = rsqrtf(var + 1e-5f);
  for (int i = t; i < HID; i += 256)
    h16[(size_t)s * HID + i] = (f16)((xs[i] - mu) * inv * g[i] + b[i]);
}

// ---------------- LayerNorm: sum16 (pre-LN, f16) -> h16 ----------------
__global__ __launch_bounds__(256) void ln_kernel(
    const f16* __restrict__ sum16, const float* __restrict__ g,
    const float* __restrict__ b, f16* __restrict__ h16) {
  int s = blockIdx.x, t = threadIdx.x;
  __shared__ float red[256];
  float x0 = (float)sum16[(size_t)s * HID + t];
  float x1 = (float)sum16[(size_t)s * HID + t + 256];
  float x2 = (float)sum16[(size_t)s * HID + t + 512];
  float mu = block_reduce_sum(x0 + x1 + x2, red) * (1.f / HID);
  float d0 = x0 - mu, d1 = x1 - mu, d2 = x2 - mu;
  float var = block_reduce_sum(d0 * d0 + d1 * d1 + d2 * d2, red) * (1.f / HID);
  float inv = rsqrtf(var + 1e-5f);
  h16[(size_t)s * HID + t] = (f16)(d0 * inv * g[t] + b[t]);
  h16[(size_t)s * HID + t + 256] = (f16)(d1 * inv * g[t + 256] + b[t + 256]);
  h16[(size_t)s * HID + t + 512] = (f16)(d2 * inv * g[t + 512] + b[t + 512]);
}

// ------ weight transpose + f16 convert, ALL layers: W[l][K][N] f32 -> WT[l][N][K] f16
__global__ __launch_bounds__(256) void wt_kernel(const float* __restrict__ W,
                                                 f16* __restrict__ WT, int K, int N) {
  size_t lo = (size_t)blockIdx.z * K * N;
  const float* Wl = W + lo;
  f16* WTl = WT + lo;
  __shared__ float tile[32][33];
  int k0 = blockIdx.y * 32, n0 = blockIdx.x * 32;
  int t = threadIdx.x;
  int r = t >> 3, c = (t & 7) * 4;
  float4 v = *(const float4*)&Wl[(size_t)(k0 + r) * N + n0 + c];
  tile[r][c] = v.x; tile[r][c + 1] = v.y; tile[r][c + 2] = v.z; tile[r][c + 3] = v.w;
  __syncthreads();
  int n = t >> 3, kq = (t & 7) * 4;
  f16x4 o = {(f16)tile[kq][n], (f16)tile[kq + 1][n], (f16)tile[kq + 2][n], (f16)tile[kq + 3][n]};
  *(f16x4*)&WTl[(size_t)(n0 + n) * K + k0 + kq] = o;
}

// ---- fp16 MFMA GEMM 128x128, single-buffer 2-barrier (proven structure) ----
#define GBK 64

template <bool GELU>
__global__ __launch_bounds__(256) void gemm_f16_kernel(
    const f16* __restrict__ A, const f16* __restrict__ BT,
    const float* __restrict__ bias, f16* __restrict__ Cout, int M, int N, int K) {
  __shared__ f16 As[128 * GBK];
  __shared__ f16 Bs[128 * GBK];
  int t = threadIdx.x, lane = t & 63, wave = t >> 6;
  int wr = wave >> 1, wc = wave & 1;
  int gx = gridDim.x;
  int nl = xcd_swz(blockIdx.y * gx + blockIdx.x, gx * gridDim.y);
  int bx = nl % gx, by = nl / gx;

  f32x4 acc[4][4];
#pragma unroll
  for (int mi = 0; mi < 4; mi++)
#pragma unroll
    for (int ni = 0; ni < 4; ni++) acc[mi][ni] = (f32x4){0.f, 0.f, 0.f, 0.f};

  const f16* Ablk = A + (size_t)(by * 128) * K;
  const f16* Bblk = BT + (size_t)(bx * 128) * K;
  int rl = lane >> 3;
  int lc = (lane & 7) ^ rl;

  for (int k0 = 0; k0 < K; k0 += GBK) {
#pragma unroll
    for (int ii = 0; ii < 4; ii++) {
      int i = wave * 4 + ii;
      int r = i * 8 + rl;
      async16(&As[i * 512], Ablk + (size_t)r * K + k0 + lc * 8);
      async16(&Bs[i * 512], Bblk + (size_t)r * K + k0 + lc * 8);
    }
    __syncthreads();
#pragma unroll
    for (int kc = 0; kc < 2; kc++) {
      f16x8 af[4], bf[4];
#pragma unroll
      for (int mi = 0; mi < 4; mi++) {
        int row = wr * 64 + mi * 16 + (lane & 15);
        int pc = (kc * 4 + (lane >> 4)) ^ (row & 7);
        af[mi] = *(const f16x8*)&As[row * 64 + pc * 8];
      }
#pragma unroll
      for (int ni = 0; ni < 4; ni++) {
        int row = wc * 64 + ni * 16 + (lane & 15);
        int pc = (kc * 4 + (lane >> 4)) ^ (row & 7);
        bf[ni] = *(const f16x8*)&Bs[row * 64 + pc * 8];
      }
#pragma unroll
      for (int mi = 0; mi < 4; mi++)
#pragma unroll
        for (int ni = 0; ni < 4; ni++)
          acc[mi][ni] = __builtin_amdgcn_mfma_f32_16x16x32_f16(af[mi], bf[ni], acc[mi][ni], 0, 0, 0);
    }
    __syncthreads();
  }

  int row_base = by * 128 + wr * 64 + (lane >> 4) * 4;
  int col_base = bx * 128 + wc * 64 + (lane & 15);
#pragma unroll
  for (int mi = 0; mi < 4; mi++) {
#pragma unroll
    for (int ni = 0; ni < 4; ni++) {
      int col = col_base + ni * 16;
      float bs = bias[col];
#pragma unroll
      for (int j = 0; j < 4; j++) {
        int row = row_base + mi * 16 + j;
        float x = acc[mi][ni][j] + bs;
        if (GELU) x = 0.5f * x * (1.f + erff(x * 0.70710678118654752f));
        Cout[(size_t)row * N + col] = (f16)x;
      }
    }
  }
}

// ---- fp16 MFMA GEMM 128x64 (N=768 outputs), optional fused residual add ----
template <bool RESID>
__global__ __launch_bounds__(256) void gemm_f16_n64_kernel(
    const f16* __restrict__ A, const f16* __restrict__ BT,
    const float* __restrict__ bias, const f16* __restrict__ resid,
    f16* __restrict__ Cout, int M, int N, int K) {
  __shared__ f16 As[128 * GBK];
  __shared__ f16 Bs[64 * GBK];
  int t = threadIdx.x, lane = t & 63, wave = t >> 6;
  int wr = wave >> 1, wc = wave & 1;
  int gx = gridDim.x;
  int nl = xcd_swz(blockIdx.y * gx + blockIdx.x, gx * gridDim.y);
  int bx = nl % gx, by = nl / gx;

  f32x4 acc[4][2];
#pragma unroll
  for (int mi = 0; mi < 4; mi++)
#pragma unroll
    for (int ni = 0; ni < 2; ni++) acc[mi][ni] = (f32x4){0.f, 0.f, 0.f, 0.f};

  const f16* Ablk = A + (size_t)(by * 128) * K;
  const f16* Bblk = BT + (size_t)(bx * 64) * K;
  int rl = lane >> 3;
  int lc = (lane & 7) ^ rl;

  for (int k0 = 0; k0 < K; k0 += GBK) {
#pragma unroll
    for (int ii = 0; ii < 4; ii++) {
      int i = wave * 4 + ii;
      int r = i * 8 + rl;
      async16(&As[i * 512], Ablk + (size_t)r * K + k0 + lc * 8);
    }
#pragma unroll
    for (int ii = 0; ii < 2; ii++) {
      int i = wave * 2 + ii;
      int r = i * 8 + rl;
      async16(&Bs[i * 512], Bblk + (size_t)r * K + k0 + lc * 8);
    }
    __syncthreads();
#pragma unroll
    for (int kc = 0; kc < 2; kc++) {
      f16x8 af[4], bf[2];
#pragma unroll
      for (int mi = 0; mi < 4; mi++) {
        int row = wr * 64 + mi * 16 + (lane & 15);
        int pc = (kc * 4 + (lane >> 4)) ^ (row & 7);
        af[mi] = *(const f16x8*)&As[row * 64 + pc * 8];
      }
#pragma unroll
      for (int ni = 0; ni < 2; ni++) {
        int row = wc * 32 + ni * 16 + (lane & 15);
        int pc = (kc * 4 + (lane >> 4)) ^ (row & 7);
        bf[ni] = *(const f16x8*)&Bs[row * 64 + pc * 8];
      }
#pragma unroll
      for (int mi = 0; mi < 4; mi++)
#pragma unroll
        for (int ni = 0; ni < 2; ni++)
          acc[mi][ni] = __builtin_amdgcn_mfma_f32_16x16x32_f16(af[mi], bf[ni], acc[mi][ni], 0, 0, 0);
    }
    __syncthreads();
  }

  int row_base = by * 128 + wr * 64 + (lane >> 4) * 4;
  int col_base = bx * 64 + wc * 32 + (lane & 15);
#pragma unroll
  for (int mi = 0; mi < 4; mi++) {
#pragma unroll
    for (int ni = 0; ni < 2; ni++) {
      int col = col_base + ni * 16;
      float bs = bias[col];
#pragma unroll
      for (int j = 0; j < 4; j++) {
        int row = row_base + mi * 16 + j;
        float x = acc[mi][ni][j] + bs;
        if (RESID) x += (float)resid[(size_t)row * N + col];
        Cout[(size_t)row * N + col] = (f16)x;
      }
    }
  }
}

// ======== fused: local windowed attention (768 blocks) + global scores (192) ========
#define ROWP 72  // padded LDS row: 64 halves + 8 pad (144B)
#define SMEM_HALVES (4 * 4608 + 64)

__global__ __launch_bounds__(256) void attn_fused_kernel(
    const f16* __restrict__ qkv, const int* __restrict__ amask,
    const int* __restrict__ gmask, const int* __restrict__ gidx,
    const float* __restrict__ gvalid, f16* __restrict__ outp,
    float* __restrict__ Sg, float2* __restrict__ cstat) {
  __shared__ __align__(16) f16 smem[SMEM_HALVES];
  int bid = blockIdx.x;
  int t = threadIdx.x, lane = t & 63, w = t >> 6;

  if (bid < NH * 64) {
    // ---------------- local attention ----------------
    int nl = xcd_swz(bid, NH * 64);
    int h = nl >> 6, qb = nl & 63;
    int q0 = qb * 64;
    int g4 = lane >> 4, l15 = lane & 15;

    f16* Qs = smem;
    f16* Kt = smem + 4608;
    f16* Vt = smem + 2 * 4608;
    f16* Pb = smem + 3 * 4608;
    float* gvs = (float*)(smem + 4 * 4608);          // 16 floats
    unsigned* kokp = (unsigned*)(gvs + NG);          // 2 unsigned

    {  // stage Q (scaled by 1/8)
      int r = t >> 2, c2 = (t & 3) * 2;
      const f16* qr = qkv + (size_t)(q0 + r) * QKV3 + h * DH + c2 * 8;
      f16x8 v0 = *(const f16x8*)qr;
      f16x8 v1 = *(const f16x8*)(qr + 8);
#pragma unroll
      for (int e = 0; e < 8; e++) { v0[e] = v0[e] * (f16)0.125f; v1[e] = v1[e] * (f16)0.125f; }
      *(f16x8*)&Qs[r * ROWP + c2 * 8] = v0;
      *(f16x8*)&Qs[r * ROWP + c2 * 8 + 8] = v1;
      if (t < NG) gvs[t] = gvalid[t];
    }
    __syncthreads();

    int qrow = w * 16 + l15;
    f16x8 qf0 = *(const f16x8*)&Qs[qrow * ROWP + g4 * 8];
    f16x8 qf1 = *(const f16x8*)&Qs[qrow * ROWP + 32 + g4 * 8];

    float mb = -50000.f, lp = 0.f;
    f32x4 oacc[4];
#pragma unroll
    for (int sd = 0; sd < 4; sd++) oacc[sd] = (f32x4){0.f, 0.f, 0.f, 0.f};

    f16* Pw = &Pb[w * 16 * ROWP];

    for (int kt = 0; kt <= 9; kt++) {
      int jb = q0 - 256 + kt * 64;
      bool isG = (kt == 9);
      if (!isG && (jb + 64 <= 0 || jb >= S)) continue;
      __syncthreads();
      {  // stage K tile [k][d]
        int k = t >> 2, c2 = (t & 3) * 2;
        int j = isG ? (k < NG ? gidx[k] : -1) : (jb + k);
        bool jv = isG ? (k < NG && gvs[k] > 0.f) : (j >= 0 && j < S);
        f16x8 v0 = {}, v1 = {};
        if (jv) {
          const f16* kr = qkv + (size_t)j * QKV3 + HID + h * DH + c2 * 8;
          v0 = *(const f16x8*)kr; v1 = *(const f16x8*)(kr + 8);
        }
        *(f16x8*)&Kt[k * ROWP + c2 * 8] = v0;
        *(f16x8*)&Kt[k * ROWP + c2 * 8 + 8] = v1;
      }
      if (w == 0) {  // key-ok bitmask
        int k = lane;
        bool ok;
        if (isG) ok = (k < NG && gvs[k] > 0.f);
        else {
          int j = jb + k;
          ok = (j >= 0 && j < S) && (amask[j] != 0) && (gmask[j] == 0);
        }
        unsigned long long m = __ballot(ok);
        if (lane == 0) { kokp[0] = (unsigned)m; kokp[1] = (unsigned)(m >> 32); }
      }
      {  // stage V transposed [d][k]
        int k2 = (t & 31) * 2, dq = (t >> 5) * 8;
        int j0 = isG ? (k2 < NG ? gidx[k2] : -1) : (jb + k2);
        int j1 = isG ? (k2 + 1 < NG ? gidx[k2 + 1] : -1) : (jb + k2 + 1);
        bool ok0 = isG ? (k2 < NG && gvs[k2] > 0.f) : (j0 >= 0 && j0 < S);
        bool ok1 = isG ? (k2 + 1 < NG && gvs[k2 + 1] > 0.f) : (j1 >= 0 && j1 < S);
        f16x8 va = {}, vb = {};
        if (ok0) va = *(const f16x8*)(qkv + (size_t)j0 * QKV3 + 2 * HID + h * DH + dq);
        if (ok1) vb = *(const f16x8*)(qkv + (size_t)j1 * QKV3 + 2 * HID + h * DH + dq);
#pragma unroll
        for (int e = 0; e < 8; e++) {
          f16x2 pr = {va[e], vb[e]};
          *(f16x2*)&Vt[(dq + e) * ROWP + k2] = pr;
        }
      }
      __syncthreads();

      unsigned long long kok = ((unsigned long long)kokp[1] << 32) | (unsigned long long)kokp[0];

      f32x4 sv[4];
      __builtin_amdgcn_s_setprio(1);
#pragma unroll
      for (int s4 = 0; s4 < 4; s4++) {
        int krow = s4 * 16 + l15;
        f16x8 ka0 = *(const f16x8*)&Kt[krow * ROWP + g4 * 8];
        f16x8 ka1 = *(const f16x8*)&Kt[krow * ROWP + 32 + g4 * 8];
        f32x4 a = {0.f, 0.f, 0.f, 0.f};
        a = __builtin_amdgcn_mfma_f32_16x16x32_f16(ka0, qf0, a, 0, 0, 0);
        a = __builtin_amdgcn_mfma_f32_16x16x32_f16(ka1, qf1, a, 0, 0, 0);
        sv[s4] = a;
      }
      __builtin_amdgcn_s_setprio(0);
      int ql = w * 16 + l15;
#pragma unroll
      for (int s4 = 0; s4 < 4; s4++)
#pragma unroll
        for (int r = 0; r < 4; r++) {
          int kl = s4 * 16 + g4 * 4 + r;
          bool ok = (kok >> kl) & 1ull;
          if (kt == 0) ok = ok && (kl >= ql);
          else if (kt == 8) ok = ok && (kl <= ql);
          sv[s4][r] = ok ? sv[s4][r] : -1e30f;
        }
      float mt = -1e30f;
#pragma unroll
      for (int s4 = 0; s4 < 4; s4++)
#pragma unroll
        for (int r = 0; r < 4; r++) mt = fmaxf(mt, sv[s4][r]);
      mt = fmaxf(mt, __shfl_xor(mt, 16));
      mt = fmaxf(mt, __shfl_xor(mt, 32));
      float mn = fmaxf(mb, mt);
      float corr = __expf(mb - mn);
      mb = mn;
      lp *= corr;
#pragma unroll
      for (int sd = 0; sd < 4; sd++)
#pragma unroll
        for (int r = 0; r < 4; r++) oacc[sd][r] *= corr;
#pragma unroll
      for (int s4 = 0; s4 < 4; s4++) {
#pragma unroll
        for (int rp = 0; rp < 2; rp++) {
          float p0 = __expf(sv[s4][rp * 2] - mn);
          float p1 = __expf(sv[s4][rp * 2 + 1] - mn);
          f16 h0 = (f16)p0, h1 = (f16)p1;
          lp += (float)h0 + (float)h1;
          int kl = s4 * 16 + g4 * 4 + rp * 2;
          f16x2 pr = {h0, h1};
          *(f16x2*)&Pw[l15 * ROWP + kl] = pr;
        }
      }
      f16x8 pf0 = *(const f16x8*)&Pw[l15 * ROWP + g4 * 8];
      f16x8 pf1 = *(const f16x8*)&Pw[l15 * ROWP + 32 + g4 * 8];
      __builtin_amdgcn_s_setprio(1);
#pragma unroll
      for (int sd = 0; sd < 4; sd++) {
        int drow = sd * 16 + l15;
        f16x8 va0 = *(const f16x8*)&Vt[drow * ROWP + g4 * 8];
        f16x8 va1 = *(const f16x8*)&Vt[drow * ROWP + 32 + g4 * 8];
        oacc[sd] = __builtin_amdgcn_mfma_f32_16x16x32_f16(va0, pf0, oacc[sd], 0, 0, 0);
        oacc[sd] = __builtin_amdgcn_mfma_f32_16x16x32_f16(va1, pf1, oacc[sd], 0, 0, 0);
      }
      __builtin_amdgcn_s_setprio(0);
    }

    float lt = lp + __shfl_xor(lp, 16);
    lt = lt + __shfl_xor(lt, 32);
    float inv = (lt > 0.f) ? 1.f / lt : 0.f;
    int qg = q0 + w * 16 + l15;
    f16* orow = outp + (size_t)qg * HID + h * DH;
#pragma unroll
    for (int sd = 0; sd < 4; sd++)
#pragma unroll
      for (int r = 0; r < 4; r++)
        orow[sd * 16 + g4 * 4 + r] = (f16)(oacc[sd][r] * inv);
  } else {
    // ---------------- global-token scores + per-chunk stats ----------------
    int gb = bid - NH * 64;
    int h = gb >> 4, jc = gb & 15;
    f16* Qs = smem;                          // [NG][DH]
    float* wred = (float*)(smem + NG * DH);  // [4][NG]
    float* cmaxs = wred + 4 * NG;            // [NG]
    if (t < 128) {
      int g = t >> 3, c = (t & 7) * 8;
      const f16* qr = qkv + (size_t)gidx[g] * QKV3 + h * DH + c;
      *(f16x8*)&Qs[g * DH + c] = *(const f16x8*)qr;
    }
    __syncthreads();
    int j = jc * 256 + t;
    const f16x8* kr = (const f16x8*)(qkv + (size_t)j * QKV3 + HID + h * DH);
    f16x8 kv[8];
#pragma unroll
    for (int c = 0; c < 8; c++) kv[c] = kr[c];
    bool ok = amask[j] != 0;
    float sg[NG];
#pragma unroll 4
    for (int g = 0; g < NG; g++) {
      float s = 0.f;
#pragma unroll
      for (int c = 0; c < 8; c++) {
        f16x8 qv = *(const f16x8*)&Qs[g * DH + c * 8];
#pragma unroll
        for (int e = 0; e < 8; e++) s += (float)qv[e] * (float)kv[c][e];
      }
      sg[g] = ok ? s * 0.125f : NEGV;
      Sg[(size_t)(h * NG + g) * S + j] = sg[g];
    }
#pragma unroll
    for (int g = 0; g < NG; g++) {
      float m = sg[g];
#pragma unroll
      for (int st = 1; st < 64; st <<= 1) m = fmaxf(m, __shfl_xor(m, st));
      if (lane == 0) wred[w * NG + g] = m;
    }
    __syncthreads();
    if (t < NG)
      cmaxs[t] = fmaxf(fmaxf(wred[t], wred[NG + t]), fmaxf(wred[2 * NG + t], wred[3 * NG + t]));
    __syncthreads();
#pragma unroll
    for (int g = 0; g < NG; g++) {
      float p = __expf(sg[g] - cmaxs[g]);
#pragma unroll
      for (int st = 1; st < 64; st <<= 1) p += __shfl_xor(p, st);
      if (lane == 0) wred[w * NG + g] = p;
    }
    __syncthreads();
    if (t < NG) {
      float s4 = wred[t] + wred[NG + t] + wred[2 * NG + t] + wred[3 * NG + t];
      cstat[((size_t)(h * NG + t)) * 16 + jc] = make_float2(cmaxs[t], s4);
    }
  }
}

// ======== global PV: one block per (h,g), loops 16 chunks, writes attn16 ========
__global__ __launch_bounds__(256) void gpv2_kernel(
    const f16* __restrict__ qkv, const float* __restrict__ Sg,
    const float2* __restrict__ cstat, const int* __restrict__ gidx,
    const float* __restrict__ gvalid, f16* __restrict__ attn16) {
  int h = blockIdx.x >> 4, g = blockIdx.x & 15;
  if (gvalid[g] <= 0.f) return;
  int hg = h * NG + g;
  int t = threadIdx.x;
  __shared__ float Ps[256];
  __shared__ f16 Vs[256][DH];
  __shared__ float red[256];
  __shared__ float msh, dinvh;
  if (t == 0) {
    const float2* cs = &cstat[(size_t)hg * 16];
    float m = -1e30f;
#pragma unroll
    for (int c = 0; c < 16; c++) m = fmaxf(m, cs[c].x);
    float den = 0.f;
#pragma unroll
    for (int c = 0; c < 16; c++) den += cs[c].y * __expf(cs[c].x - m);
    msh = m;
    dinvh = den > 0.f ? 1.f / den : 0.f;
  }
  __syncthreads();
  float m = msh, dinv = dinvh;
  int d = t & 63, grp = t >> 6;
  float o = 0.f;
  for (int jc = 0; jc < 16; jc++) {
    int jb = jc * 256;
    Ps[t] = __expf(Sg[(size_t)hg * S + jb + t] - m) * dinv;
    {
      int r = t >> 3, c = (t & 7) * 8;
#pragma unroll
      for (int pp = 0; pp < 8; pp++) {
        int row = pp * 32 + r;
        const f16* vr = qkv + (size_t)(jb + row) * QKV3 + 2 * HID + h * DH + c;
        *(f16x8*)&Vs[row][c] = *(const f16x8*)vr;
      }
    }
    __syncthreads();
#pragma unroll 8
    for (int j = grp; j < 256; j += 4) o += Ps[j] * (float)Vs[j][d];
    __syncthreads();
  }
  red[grp * 64 + d] = o;
  __syncthreads();
  if (t < 64) {
    float oo = red[t] + red[64 + t] + red[128 + t] + red[192 + t];
    attn16[(size_t)gidx[g] * HID + h * DH + t] = (f16)oo;
  }
}

// ---------------- masked mean pool (partials) + classifier head ----------------
__global__ __launch_bounds__(256) void pool_part_kernel(
    const f16* __restrict__ h, const int* __restrict__ amask, float* __restrict__ part) {
  int b = blockIdx.x, t = threadIdx.x;
  float a0 = 0.f, a1 = 0.f, a2 = 0.f;
  for (int r = 0; r < 64; r++) {
    int s = b * 64 + r;
    float w = (float)amask[s];
    const f16* hr = h + (size_t)s * HID;
    a0 += (float)hr[t] * w;
    a1 += (float)hr[t + 256] * w;
    a2 += (float)hr[t + 512] * w;
  }
  part[(size_t)b * HID + t] = a0;
  part[(size_t)b * HID + t + 256] = a1;
  part[(size_t)b * HID + t + 512] = a2;
}

__global__ __launch_bounds__(256) void cls_head_kernel(
    const float* __restrict__ part, const int* __restrict__ amask,
    const float* __restrict__ clsW, const float* __restrict__ clsb,
    float* __restrict__ out) {
  __shared__ float pooled[HID];
  __shared__ float red[256];
  int t = threadIdx.x;
  for (int i = t; i < HID; i += 256) {
    float s = 0.f;
    for (int b2 = 0; b2 < 64; b2++) s += part[(size_t)b2 * HID + i];
    pooled[i] = s;
  }
  float c = 0.f;
  for (int s2 = t; s2 < S; s2 += 256) c += (float)amask[s2];
  float cnt = block_reduce_sum(c, red);
  float p0 = 0.f, p1 = 0.f;
  for (int i = t; i < HID; i += 256) {
    float pv = pooled[i] / cnt;
    p0 += pv * clsW[i * 2];
    p1 += pv * clsW[i * 2 + 1];
  }
  float s0 = block_reduce_sum(p0, red);
  float s1 = block_reduce_sum(p1, red);
  if (t == 0) { out[0] = s0 + clsb[0]; out[1] = s1 + clsb[1]; }
}

// ---------------- launch ----------------
extern "C" void kernel_launch(void* const* d_in, const int* in_sizes, int n_in,
                              void* d_out, int out_size, void* d_ws, size_t ws_size,
                              hipStream_t stream) {
  const int* ids = (const int*)d_in[0];
  const int* amask = (const int*)d_in[1];
  const int* gmask = (const int*)d_in[2];
  const float* tok = (const float*)d_in[3];
  const float* pos = (const float*)d_in[4];
  const float* elnw = (const float*)d_in[5];
  const float* elnb = (const float*)d_in[6];
  const float* Wqkv = (const float*)d_in[7];
  const float* bqkv = (const float*)d_in[8];
  const float* Wo = (const float*)d_in[9];
  const float* bo = (const float*)d_in[10];
  const float* ln1w = (const float*)d_in[11];
  const float* ln1b = (const float*)d_in[12];
  const float* W1 = (const float*)d_in[13];
  const float* b1 = (const float*)d_in[14];
  const float* W2 = (const float*)d_in[15];
  const float* b2 = (const float*)d_in[16];
  const float* ln2w = (const float*)d_in[17];
  const float* ln2b = (const float*)d_in[18];
  const float* clsW = (const float*)d_in[19];
  const float* clsb = (const float*)d_in[20];

  char* w8 = (char*)d_ws;
  size_t o = 0;
  f16* h16 = (f16*)(w8 + o); o += (size_t)S * HID * 2;
  f16* qkv16 = (f16*)(w8 + o); o += (size_t)S * QKV3 * 2;
  f16* attn16 = (f16*)(w8 + o); o += (size_t)S * HID * 2;
  f16* ff16 = (f16*)(w8 + o); o += (size_t)S * FF * 2;
  f16* sum16 = (f16*)(w8 + o); o += (size_t)S * HID * 2;
  float* part = (float*)(w8 + o); o += (size_t)64 * HID * 4;
  int* gidx = (int*)(w8 + o); o += 64;
  float* gvalid = (float*)(w8 + o); o += 64;
  f16* WqkvT = (f16*)(w8 + o); o += (size_t)NLAYER * HID * QKV3 * 2;
  f16* WoT = (f16*)(w8 + o); o += (size_t)NLAYER * HID * HID * 2;
  f16* W1T = (f16*)(w8 + o); o += (size_t)NLAYER * HID * FF * 2;
  f16* W2T = (f16*)(w8 + o); o += (size_t)NLAYER * FF * HID * 2;
  float* Sg = (float*)(w8 + o); o += (size_t)NH * NG * S * 4;
  float2* cstat = (float2*)(w8 + o); o += (size_t)NH * NG * 16 * 8;

  gidx_kernel<<<1, 64, 0, stream>>>(gmask, gidx, gvalid);
  embed_ln_kernel<<<S, 256, 0, stream>>>(ids, tok, pos, elnw, elnb, h16);
  wt_kernel<<<dim3(QKV3 / 32, HID / 32, NLAYER), 256, 0, stream>>>(Wqkv, WqkvT, HID, QKV3);
  wt_kernel<<<dim3(HID / 32, HID / 32, NLAYER), 256, 0, stream>>>(Wo, WoT, HID, HID);
  wt_kernel<<<dim3(FF / 32, HID / 32, NLAYER), 256, 0, stream>>>(W1, W1T, HID, FF);
  wt_kernel<<<dim3(HID / 32, FF / 32, NLAYER), 256, 0, stream>>>(W2, W2T, FF, HID);

  for (int l = 0; l < NLAYER; l++) {
    gemm_f16_kernel<false><<<dim3(QKV3 / 128, S / 128), 256, 0, stream>>>(
        h16, WqkvT + (size_t)l * HID * QKV3, bqkv + (size_t)l * QKV3, qkv16, S, QKV3, HID);
    attn_fused_kernel<<<NH * 64 + NH * 16, 256, 0, stream>>>(
        qkv16, amask, gmask, gidx, gvalid, attn16, Sg, cstat);
    gpv2_kernel<<<NH * NG, 256, 0, stream>>>(qkv16, Sg, cstat, gidx, gvalid, attn16);
    gemm_f16_n64_kernel<true><<<dim3(HID / 64, S / 128), 256, 0, stream>>>(
        attn16, WoT + (size_t)l * HID * HID, bo + (size_t)l * HID, h16, sum16, S, HID, HID);
    ln_kernel<<<S, 256, 0, stream>>>(sum16, ln1w + (size_t)l * HID, ln1b + (size_t)l * HID, h16);
    gemm_f16_kernel<true><<<dim3(FF / 128, S / 128), 256, 0, stream>>>(
        h16, W1T + (size_t)l * HID * FF, b1 + (size_t)l * FF, ff16, S, FF, HID);
    gemm_f16_n64_kernel<true><<<dim3(HID / 64, S / 128), 256, 0, stream>>>(
        ff16, W2T + (size_t)l * FF * HID, b2 + (size_t)l * HID, h16, sum16, S, HID, FF);
    ln_kernel<<<S, 256, 0, stream>>>(sum16, ln2w + (size_t)l * HID, ln2b + (size_t)l * HID, h16);
  }
  pool_part_kernel<<<64, 256, 0, stream>>>(h16, amask, part);
  cls_head_kernel<<<1, 256, 0, stream>>>(part, amask, clsW, clsb, (float*)d_out);
}

// Round 9
// 2547.370 us; speedup vs baseline: 1.0597x; 1.0597x over previous
//
#include <hip/hip_runtime.h>
#include <cmath>

#define S 4096
#define HID 768
#define NH 12
#define DH 64
#define CHUNK 256
#define NC (S / CHUNK)
#define NG 16
#define FF 3072
#define NLAYER 12
#define QKV3 (3 * HID)
#define NEGV -1e9f

typedef _Float16 f16;
typedef __attribute__((ext_vector_type(2))) _Float16 f16x2;
typedef __attribute__((ext_vector_type(4))) _Float16 f16x4;
typedef __attribute__((ext_vector_type(8))) _Float16 f16x8;
typedef __attribute__((ext_vector_type(4))) float f32x4;

__device__ __forceinline__ void async16(f16* lds, const f16* g) {
  __builtin_amdgcn_global_load_lds((const __attribute__((address_space(1))) unsigned int*)g,
                                   (__attribute__((address_space(3))) unsigned int*)lds,
                                   16, 0, 0);
}

// bijective XCD swizzle for nwg % 8 == 0
__device__ __forceinline__ int xcd_swz(int lin, int nwg) {
  return (lin & 7) * (nwg >> 3) + (lin >> 3);
}

__device__ __forceinline__ float block_reduce_sum(float v, float* red) {
  int t = threadIdx.x;
  red[t] = v; __syncthreads();
  for (int st = 128; st > 0; st >>= 1) {
    if (t < st) red[t] += red[t + st];
    __syncthreads();
  }
  float r = red[0]; __syncthreads();
  return r;
}

// ---------------- gidx / gvalid (matches jax top_k semantics) ----------------
__global__ void gidx_kernel(const int* __restrict__ gmask, int* __restrict__ gidx,
                            float* __restrict__ gvalid) {
  if (threadIdx.x != 0 || blockIdx.x != 0) return;
  int cnt = 0;
  for (int s = 0; s < S && cnt < NG; s++)
    if (gmask[s] > 0) { gidx[cnt] = s; gvalid[cnt] = 1.f; cnt++; }
  for (int s = 0; s < S && cnt < NG; s++)
    if (gmask[s] == 0) { gidx[cnt] = s; gvalid[cnt] = 0.f; cnt++; }
}

// ---------------- embedding + LayerNorm (writes f16 residual stream) ----------------
__global__ __launch_bounds__(256) void embed_ln_kernel(
    const int* __restrict__ ids, const float* __restrict__ tok,
    const float* __restrict__ pos, const float* __restrict__ g,
    const float* __restrict__ b, f16* __restrict__ h16) {
  int s = blockIdx.x, t = threadIdx.x;
  __shared__ float xs[HID];
  __shared__ float red[256];
  const float* tr = tok + (size_t)ids[s] * HID;
  const float* pr = pos + (size_t)s * HID;
  float ls = 0.f;
  for (int i = t; i < HID; i += 256) { float v = tr[i] + pr[i]; xs[i] = v; ls += v; }
  float mu = block_reduce_sum(ls, red) * (1.f / HID);
  float lv = 0.f;
  for (int i = t; i < HID; i += 256) { float d = xs[i] - mu; lv += d * d; }
  float var = block_reduce_sum(lv, red) * (1.f / HID);
  float inv = rsqrtf(var + 1e-5f);
  for (int i = t; i < HID; i += 256)
    h16[(size_t)s * HID + i] = (f16)((xs[i] - mu) * inv * g[i] + b[i]);
}

// ---------------- LayerNorm: sum16 (pre-LN, f16) -> h16 ----------------
__global__ __launch_bounds__(256) void ln_kernel(
    const f16* __restrict__ sum16, const float* __restrict__ g,
    const float* __restrict__ b, f16* __restrict__ h16) {
  int s = blockIdx.x, t = threadIdx.x;
  __shared__ float red[256];
  float x0 = (float)sum16[(size_t)s * HID + t];
  float x1 = (float)sum16[(size_t)s * HID + t + 256];
  float x2 = (float)sum16[(size_t)s * HID + t + 512];
  float mu = block_reduce_sum(x0 + x1 + x2, red) * (1.f / HID);
  float d0 = x0 - mu, d1 = x1 - mu, d2 = x2 - mu;
  float var = block_reduce_sum(d0 * d0 + d1 * d1 + d2 * d2, red) * (1.f / HID);
  float inv = rsqrtf(var + 1e-5f);
  h16[(size_t)s * HID + t] = (f16)(d0 * inv * g[t] + b[t]);
  h16[(size_t)s * HID + t + 256] = (f16)(d1 * inv * g[t + 256] + b[t + 256]);
  h16[(size_t)s * HID + t + 512] = (f16)(d2 * inv * g[t + 512] + b[t + 512]);
}

// ------ weight transpose + f16 convert, ALL layers: W[l][K][N] f32 -> WT[l][N][K] f16
__global__ __launch_bounds__(256) void wt_kernel(const float* __restrict__ W,
                                                 f16* __restrict__ WT, int K, int N) {
  size_t lo = (size_t)blockIdx.z * K * N;
  const float* Wl = W + lo;
  f16* WTl = WT + lo;
  __shared__ float tile[32][33];
  int k0 = blockIdx.y * 32, n0 = blockIdx.x * 32;
  int t = threadIdx.x;
  int r = t >> 3, c = (t & 7) * 4;
  float4 v = *(const float4*)&Wl[(size_t)(k0 + r) * N + n0 + c];
  tile[r][c] = v.x; tile[r][c + 1] = v.y; tile[r][c + 2] = v.z; tile[r][c + 3] = v.w;
  __syncthreads();
  int n = t >> 3, kq = (t & 7) * 4;
  f16x4 o = {(f16)tile[kq][n], (f16)tile[kq + 1][n], (f16)tile[kq + 2][n], (f16)tile[kq + 3][n]};
  *(f16x4*)&WTl[(size_t)(n0 + n) * K + k0 + kq] = o;
}

// ---- fp16 MFMA GEMM 128x128, single-buffer 2-barrier (proven structure) ----
#define GBK 64

template <bool GELU>
__global__ __launch_bounds__(256) void gemm_f16_kernel(
    const f16* __restrict__ A, const f16* __restrict__ BT,
    const float* __restrict__ bias, f16* __restrict__ Cout, int M, int N, int K) {
  __shared__ f16 As[128 * GBK];
  __shared__ f16 Bs[128 * GBK];
  int t = threadIdx.x, lane = t & 63, wave = t >> 6;
  int wr = wave >> 1, wc = wave & 1;
  int gx = gridDim.x;
  int nl = xcd_swz(blockIdx.y * gx + blockIdx.x, gx * gridDim.y);
  int bx = nl % gx, by = nl / gx;

  f32x4 acc[4][4];
#pragma unroll
  for (int mi = 0; mi < 4; mi++)
#pragma unroll
    for (int ni = 0; ni < 4; ni++) acc[mi][ni] = (f32x4){0.f, 0.f, 0.f, 0.f};

  const f16* Ablk = A + (size_t)(by * 128) * K;
  const f16* Bblk = BT + (size_t)(bx * 128) * K;
  int rl = lane >> 3;
  int lc = (lane & 7) ^ rl;

  for (int k0 = 0; k0 < K; k0 += GBK) {
#pragma unroll
    for (int ii = 0; ii < 4; ii++) {
      int i = wave * 4 + ii;
      int r = i * 8 + rl;
      async16(&As[i * 512], Ablk + (size_t)r * K + k0 + lc * 8);
      async16(&Bs[i * 512], Bblk + (size_t)r * K + k0 + lc * 8);
    }
    __syncthreads();
#pragma unroll
    for (int kc = 0; kc < 2; kc++) {
      f16x8 af[4], bf[4];
#pragma unroll
      for (int mi = 0; mi < 4; mi++) {
        int row = wr * 64 + mi * 16 + (lane & 15);
        int pc = (kc * 4 + (lane >> 4)) ^ (row & 7);
        af[mi] = *(const f16x8*)&As[row * 64 + pc * 8];
      }
#pragma unroll
      for (int ni = 0; ni < 4; ni++) {
        int row = wc * 64 + ni * 16 + (lane & 15);
        int pc = (kc * 4 + (lane >> 4)) ^ (row & 7);
        bf[ni] = *(const f16x8*)&Bs[row * 64 + pc * 8];
      }
#pragma unroll
      for (int mi = 0; mi < 4; mi++)
#pragma unroll
        for (int ni = 0; ni < 4; ni++)
          acc[mi][ni] = __builtin_amdgcn_mfma_f32_16x16x32_f16(af[mi], bf[ni], acc[mi][ni], 0, 0, 0);
    }
    __syncthreads();
  }

  int row_base = by * 128 + wr * 64 + (lane >> 4) * 4;
  int col_base = bx * 128 + wc * 64 + (lane & 15);
#pragma unroll
  for (int mi = 0; mi < 4; mi++) {
#pragma unroll
    for (int ni = 0; ni < 4; ni++) {
      int col = col_base + ni * 16;
      float bs = bias[col];
#pragma unroll
      for (int j = 0; j < 4; j++) {
        int row = row_base + mi * 16 + j;
        float x = acc[mi][ni][j] + bs;
        if (GELU) x = 0.5f * x * (1.f + erff(x * 0.70710678118654752f));
        Cout[(size_t)row * N + col] = (f16)x;
      }
    }
  }
}

// ---- fp16 MFMA GEMM 128x64 (N=768 outputs), fused residual add ----
template <bool RESID>
__global__ __launch_bounds__(256) void gemm_f16_n64_kernel(
    const f16* __restrict__ A, const f16* __restrict__ BT,
    const float* __restrict__ bias, const f16* __restrict__ resid,
    f16* __restrict__ Cout, int M, int N, int K) {
  __shared__ f16 As[128 * GBK];
  __shared__ f16 Bs[64 * GBK];
  int t = threadIdx.x, lane = t & 63, wave = t >> 6;
  int wr = wave >> 1, wc = wave & 1;
  int gx = gridDim.x;
  int nl = xcd_swz(blockIdx.y * gx + blockIdx.x, gx * gridDim.y);
  int bx = nl % gx, by = nl / gx;

  f32x4 acc[4][2];
#pragma unroll
  for (int mi = 0; mi < 4; mi++)
#pragma unroll
    for (int ni = 0; ni < 2; ni++) acc[mi][ni] = (f32x4){0.f, 0.f, 0.f, 0.f};

  const f16* Ablk = A + (size_t)(by * 128) * K;
  const f16* Bblk = BT + (size_t)(bx * 64) * K;
  int rl = lane >> 3;
  int lc = (lane & 7) ^ rl;

  for (int k0 = 0; k0 < K; k0 += GBK) {
#pragma unroll
    for (int ii = 0; ii < 4; ii++) {
      int i = wave * 4 + ii;
      int r = i * 8 + rl;
      async16(&As[i * 512], Ablk + (size_t)r * K + k0 + lc * 8);
    }
#pragma unroll
    for (int ii = 0; ii < 2; ii++) {
      int i = wave * 2 + ii;
      int r = i * 8 + rl;
      async16(&Bs[i * 512], Bblk + (size_t)r * K + k0 + lc * 8);
    }
    __syncthreads();
#pragma unroll
    for (int kc = 0; kc < 2; kc++) {
      f16x8 af[4], bf[2];
#pragma unroll
      for (int mi = 0; mi < 4; mi++) {
        int row = wr * 64 + mi * 16 + (lane & 15);
        int pc = (kc * 4 + (lane >> 4)) ^ (row & 7);
        af[mi] = *(const f16x8*)&As[row * 64 + pc * 8];
      }
#pragma unroll
      for (int ni = 0; ni < 2; ni++) {
        int row = wc * 32 + ni * 16 + (lane & 15);
        int pc = (kc * 4 + (lane >> 4)) ^ (row & 7);
        bf[ni] = *(const f16x8*)&Bs[row * 64 + pc * 8];
      }
#pragma unroll
      for (int mi = 0; mi < 4; mi++)
#pragma unroll
        for (int ni = 0; ni < 2; ni++)
          acc[mi][ni] = __builtin_amdgcn_mfma_f32_16x16x32_f16(af[mi], bf[ni], acc[mi][ni], 0, 0, 0);
    }
    __syncthreads();
  }

  int row_base = by * 128 + wr * 64 + (lane >> 4) * 4;
  int col_base = bx * 64 + wc * 32 + (lane & 15);
#pragma unroll
  for (int mi = 0; mi < 4; mi++) {
#pragma unroll
    for (int ni = 0; ni < 2; ni++) {
      int col = col_base + ni * 16;
      float bs = bias[col];
#pragma unroll
      for (int j = 0; j < 4; j++) {
        int row = row_base + mi * 16 + j;
        float x = acc[mi][ni][j] + bs;
        if (RESID) x += (float)resid[(size_t)row * N + col];
        Cout[(size_t)row * N + col] = (f16)x;
      }
    }
  }
}

// ---------------- MFMA local windowed attention (separate kernel, round-7) ----------------
#define ROWP 72  // padded LDS row: 64 halves + 8 pad (144B)

__global__ __launch_bounds__(256) void local_attn_mfma_kernel(
    const f16* __restrict__ qkv, const int* __restrict__ amask,
    const int* __restrict__ gmask, const int* __restrict__ gidx,
    const float* __restrict__ gvalid, f16* __restrict__ outp) {
  int nl = xcd_swz(blockIdx.x, NH * 64);
  int h = nl >> 6;
  int qb = nl & 63;
  int q0 = qb * 64;
  int t = threadIdx.x, lane = t & 63, w = t >> 6;
  int g4 = lane >> 4, l15 = lane & 15;

  __shared__ f16 Qs[64 * ROWP];
  __shared__ f16 Kt[64 * ROWP];
  __shared__ f16 Vt[64 * ROWP];
  __shared__ f16 Pb[4 * 16 * ROWP];
  __shared__ unsigned kokLo, kokHi;
  __shared__ float gvs[NG];

  {  // stage Q (scaled by 1/8)
    int r = t >> 2, c2 = (t & 3) * 2;
    const f16* qr = qkv + (size_t)(q0 + r) * QKV3 + h * DH + c2 * 8;
    f16x8 v0 = *(const f16x8*)qr;
    f16x8 v1 = *(const f16x8*)(qr + 8);
#pragma unroll
    for (int e = 0; e < 8; e++) { v0[e] = v0[e] * (f16)0.125f; v1[e] = v1[e] * (f16)0.125f; }
    *(f16x8*)&Qs[r * ROWP + c2 * 8] = v0;
    *(f16x8*)&Qs[r * ROWP + c2 * 8 + 8] = v1;
    if (t < NG) gvs[t] = gvalid[t];
  }
  __syncthreads();

  int qrow = w * 16 + l15;
  f16x8 qf0 = *(const f16x8*)&Qs[qrow * ROWP + g4 * 8];
  f16x8 qf1 = *(const f16x8*)&Qs[qrow * ROWP + 32 + g4 * 8];

  float mb = -50000.f, lp = 0.f;
  f32x4 oacc[4];
#pragma unroll
  for (int sd = 0; sd < 4; sd++) oacc[sd] = (f32x4){0.f, 0.f, 0.f, 0.f};

  f16* Pw = &Pb[w * 16 * ROWP];

  for (int kt = 0; kt <= 9; kt++) {
    int jb = q0 - 256 + kt * 64;
    bool isG = (kt == 9);
    if (!isG && (jb + 64 <= 0 || jb >= S)) continue;
    __syncthreads();
    {  // stage K tile [k][d]
      int k = t >> 2, c2 = (t & 3) * 2;
      int j = isG ? (k < NG ? gidx[k] : -1) : (jb + k);
      bool jv = isG ? (k < NG && gvs[k] > 0.f) : (j >= 0 && j < S);
      f16x8 v0 = {}, v1 = {};
      if (jv) {
        const f16* kr = qkv + (size_t)j * QKV3 + HID + h * DH + c2 * 8;
        v0 = *(const f16x8*)kr; v1 = *(const f16x8*)(kr + 8);
      }
      *(f16x8*)&Kt[k * ROWP + c2 * 8] = v0;
      *(f16x8*)&Kt[k * ROWP + c2 * 8 + 8] = v1;
    }
    if (w == 0) {  // key-ok bitmask
      int k = lane;
      bool ok;
      if (isG) ok = (k < NG && gvs[k] > 0.f);
      else {
        int j = jb + k;
        ok = (j >= 0 && j < S) && (amask[j] != 0) && (gmask[j] == 0);
      }
      unsigned long long m = __ballot(ok);
      if (lane == 0) { kokLo = (unsigned)m; kokHi = (unsigned)(m >> 32); }
    }
    {  // stage V transposed [d][k]
      int k2 = (t & 31) * 2, dq = (t >> 5) * 8;
      int j0 = isG ? (k2 < NG ? gidx[k2] : -1) : (jb + k2);
      int j1 = isG ? (k2 + 1 < NG ? gidx[k2 + 1] : -1) : (jb + k2 + 1);
      bool ok0 = isG ? (k2 < NG && gvs[k2] > 0.f) : (j0 >= 0 && j0 < S);
      bool ok1 = isG ? (k2 + 1 < NG && gvs[k2 + 1] > 0.f) : (j1 >= 0 && j1 < S);
      f16x8 va = {}, vb = {};
      if (ok0) va = *(const f16x8*)(qkv + (size_t)j0 * QKV3 + 2 * HID + h * DH + dq);
      if (ok1) vb = *(const f16x8*)(qkv + (size_t)j1 * QKV3 + 2 * HID + h * DH + dq);
#pragma unroll
      for (int e = 0; e < 8; e++) {
        f16x2 pr = {va[e], vb[e]};
        *(f16x2*)&Vt[(dq + e) * ROWP + k2] = pr;
      }
    }
    __syncthreads();

    unsigned long long kok = ((unsigned long long)kokHi << 32) | (unsigned long long)kokLo;

    f32x4 sv[4];
    __builtin_amdgcn_s_setprio(1);
#pragma unroll
    for (int s4 = 0; s4 < 4; s4++) {
      int krow = s4 * 16 + l15;
      f16x8 ka0 = *(const f16x8*)&Kt[krow * ROWP + g4 * 8];
      f16x8 ka1 = *(const f16x8*)&Kt[krow * ROWP + 32 + g4 * 8];
      f32x4 a = {0.f, 0.f, 0.f, 0.f};
      a = __builtin_amdgcn_mfma_f32_16x16x32_f16(ka0, qf0, a, 0, 0, 0);
      a = __builtin_amdgcn_mfma_f32_16x16x32_f16(ka1, qf1, a, 0, 0, 0);
      sv[s4] = a;
    }
    __builtin_amdgcn_s_setprio(0);
    int ql = w * 16 + l15;
#pragma unroll
    for (int s4 = 0; s4 < 4; s4++)
#pragma unroll
      for (int r = 0; r < 4; r++) {
        int kl = s4 * 16 + g4 * 4 + r;
        bool ok = (kok >> kl) & 1ull;
        if (kt == 0) ok = ok && (kl >= ql);
        else if (kt == 8) ok = ok && (kl <= ql);
        sv[s4][r] = ok ? sv[s4][r] : -1e30f;
      }
    float mt = -1e30f;
#pragma unroll
    for (int s4 = 0; s4 < 4; s4++)
#pragma unroll
      for (int r = 0; r < 4; r++) mt = fmaxf(mt, sv[s4][r]);
    mt = fmaxf(mt, __shfl_xor(mt, 16));
    mt = fmaxf(mt, __shfl_xor(mt, 32));
    float mn = fmaxf(mb, mt);
    float corr = __expf(mb - mn);
    mb = mn;
    lp *= corr;
#pragma unroll
    for (int sd = 0; sd < 4; sd++)
#pragma unroll
      for (int r = 0; r < 4; r++) oacc[sd][r] *= corr;
#pragma unroll
    for (int s4 = 0; s4 < 4; s4++) {
#pragma unroll
      for (int rp = 0; rp < 2; rp++) {
        float p0 = __expf(sv[s4][rp * 2] - mn);
        float p1 = __expf(sv[s4][rp * 2 + 1] - mn);
        f16 h0 = (f16)p0, h1 = (f16)p1;
        lp += (float)h0 + (float)h1;
        int kl = s4 * 16 + g4 * 4 + rp * 2;
        f16x2 pr = {h0, h1};
        *(f16x2*)&Pw[l15 * ROWP + kl] = pr;
      }
    }
    f16x8 pf0 = *(const f16x8*)&Pw[l15 * ROWP + g4 * 8];
    f16x8 pf1 = *(const f16x8*)&Pw[l15 * ROWP + 32 + g4 * 8];
    __builtin_amdgcn_s_setprio(1);
#pragma unroll
    for (int sd = 0; sd < 4; sd++) {
      int drow = sd * 16 + l15;
      f16x8 va0 = *(const f16x8*)&Vt[drow * ROWP + g4 * 8];
      f16x8 va1 = *(const f16x8*)&Vt[drow * ROWP + 32 + g4 * 8];
      oacc[sd] = __builtin_amdgcn_mfma_f32_16x16x32_f16(va0, pf0, oacc[sd], 0, 0, 0);
      oacc[sd] = __builtin_amdgcn_mfma_f32_16x16x32_f16(va1, pf1, oacc[sd], 0, 0, 0);
    }
    __builtin_amdgcn_s_setprio(0);
  }

  float lt = lp + __shfl_xor(lp, 16);
  lt = lt + __shfl_xor(lt, 32);
  float inv = (lt > 0.f) ? 1.f / lt : 0.f;
  int qg = q0 + w * 16 + l15;
  f16* orow = outp + (size_t)qg * HID + h * DH;
#pragma unroll
  for (int sd = 0; sd < 4; sd++)
#pragma unroll
    for (int r = 0; r < 4; r++)
      orow[sd * 16 + g4 * 4 + r] = (f16)(oacc[sd][r] * inv);
}

// ============ global-token attention, split-K pipeline (round-7 structure) ============
// GA1: scores + per-chunk (max, sumexp) stats. grid = NH*16.
__global__ __launch_bounds__(256) void gscore_kernel(
    const f16* __restrict__ qkv, const int* __restrict__ amask,
    const int* __restrict__ gidx, float* __restrict__ Sg, float2* __restrict__ cstat) {
  int h = blockIdx.x >> 4, jc = blockIdx.x & 15;
  int t = threadIdx.x, lane = t & 63, w = t >> 6;
  __shared__ f16 Qs[NG][DH];
  __shared__ float wred[4][NG];
  __shared__ float cmaxs[NG];
  if (t < 128) {
    int g = t >> 3, c = (t & 7) * 8;
    const f16* qr = qkv + (size_t)gidx[g] * QKV3 + h * DH + c;
    *(f16x8*)&Qs[g][c] = *(const f16x8*)qr;
  }
  __syncthreads();
  int j = jc * 256 + t;
  const f16x8* kr = (const f16x8*)(qkv + (size_t)j * QKV3 + HID + h * DH);
  f16x8 kv[8];
#pragma unroll
  for (int c = 0; c < 8; c++) kv[c] = kr[c];
  bool ok = amask[j] != 0;
  float sg[NG];
#pragma unroll 4
  for (int g = 0; g < NG; g++) {
    float s = 0.f;
#pragma unroll
    for (int c = 0; c < 8; c++) {
      f16x8 qv = *(const f16x8*)&Qs[g][c * 8];
#pragma unroll
      for (int e = 0; e < 8; e++) s += (float)qv[e] * (float)kv[c][e];
    }
    sg[g] = ok ? s * 0.125f : NEGV;
    Sg[(size_t)(h * NG + g) * S + j] = sg[g];
  }
#pragma unroll
  for (int g = 0; g < NG; g++) {
    float m = sg[g];
#pragma unroll
    for (int st = 1; st < 64; st <<= 1) m = fmaxf(m, __shfl_xor(m, st));
    if (lane == 0) wred[w][g] = m;
  }
  __syncthreads();
  if (t < NG)
    cmaxs[t] = fmaxf(fmaxf(wred[0][t], wred[1][t]), fmaxf(wred[2][t], wred[3][t]));
  __syncthreads();
#pragma unroll
  for (int g = 0; g < NG; g++) {
    float p = __expf(sg[g] - cmaxs[g]);
#pragma unroll
    for (int st = 1; st < 64; st <<= 1) p += __shfl_xor(p, st);
    if (lane == 0) wred[w][g] = p;
  }
  __syncthreads();
  if (t < NG) {
    float s4 = wred[0][t] + wred[1][t] + wred[2][t] + wred[3][t];
    cstat[((size_t)(h * NG + t)) * 16 + jc] = make_float2(cmaxs[t], s4);
  }
}

// GA2: PV split-K partials (chunk-parallel; combines chunk stats). grid = NH*16.
__global__ __launch_bounds__(256) void gpv_kernel(
    const f16* __restrict__ qkv, const float* __restrict__ Sg,
    const float2* __restrict__ cstat, float* __restrict__ part) {
  int h = blockIdx.x >> 4, jc = blockIdx.x & 15;
  int jb = jc * 256;
  int t = threadIdx.x;
  __shared__ float Ps[NG][256];
  __shared__ f16 Vs[256][DH];
  __shared__ float ms[NG], dinv[NG];
  if (t < NG) {
    const float2* cs = &cstat[((size_t)(h * NG + t)) * 16];
    float m = -1e30f;
#pragma unroll
    for (int c = 0; c < 16; c++) m = fmaxf(m, cs[c].x);
    float den = 0.f;
#pragma unroll
    for (int c = 0; c < 16; c++) den += cs[c].y * __expf(cs[c].x - m);
    ms[t] = m;
    dinv[t] = den > 0.f ? 1.f / den : 0.f;
  }
  __syncthreads();
#pragma unroll
  for (int g = 0; g < NG; g++)
    Ps[g][t] = __expf(Sg[(size_t)(h * NG + g) * S + jb + t] - ms[g]) * dinv[g];
  {
    int r = t >> 3, c = (t & 7) * 8;
#pragma unroll
    for (int pp = 0; pp < 8; pp++) {
      int row = pp * 32 + r;
      const f16* vr = qkv + (size_t)(jb + row) * QKV3 + 2 * HID + h * DH + c;
      *(f16x8*)&Vs[row][c] = *(const f16x8*)vr;
    }
  }
  __syncthreads();
  int d = t & 63, g4 = t >> 6;
  float o0 = 0.f, o1 = 0.f, o2 = 0.f, o3 = 0.f;
#pragma unroll 8
  for (int j = 0; j < 256; j++) {
    float v = (float)Vs[j][d];
    o0 += Ps[g4][j] * v;
    o1 += Ps[g4 + 4][j] * v;
    o2 += Ps[g4 + 8][j] * v;
    o3 += Ps[g4 + 12][j] * v;
  }
  size_t base = ((size_t)h * NG) * 16 * 64;
  part[base + ((size_t)(g4) * 16 + jc) * 64 + d] = o0;
  part[base + ((size_t)(g4 + 4) * 16 + jc) * 64 + d] = o1;
  part[base + ((size_t)(g4 + 8) * 16 + jc) * 64 + d] = o2;
  part[base + ((size_t)(g4 + 12) * 16 + jc) * 64 + d] = o3;
}

// GA3: reduce partials, overwrite valid global rows. grid = NH*NG, 64 threads.
__global__ __launch_bounds__(64) void gout_kernel(
    const float* __restrict__ part, const int* __restrict__ gidx,
    const float* __restrict__ gvalid, f16* __restrict__ attn16) {
  int h = blockIdx.x >> 4, g = blockIdx.x & 15;
  if (gvalid[g] <= 0.f) return;
  int d = threadIdx.x;
  const float* pr = part + (((size_t)(h * NG + g)) * 16) * 64 + d;
  float s = 0.f;
#pragma unroll
  for (int jc = 0; jc < 16; jc++) s += pr[jc * 64];
  attn16[(size_t)gidx[g] * HID + h * DH + d] = (f16)s;
}

// ---------------- masked mean pool (partials) + classifier head ----------------
__global__ __launch_bounds__(256) void pool_part_kernel(
    const f16* __restrict__ h, const int* __restrict__ amask, float* __restrict__ part) {
  int b = blockIdx.x, t = threadIdx.x;
  float a0 = 0.f, a1 = 0.f, a2 = 0.f;
  for (int r = 0; r < 64; r++) {
    int s = b * 64 + r;
    float w = (float)amask[s];
    const f16* hr = h + (size_t)s * HID;
    a0 += (float)hr[t] * w;
    a1 += (float)hr[t + 256] * w;
    a2 += (float)hr[t + 512] * w;
  }
  part[(size_t)b * HID + t] = a0;
  part[(size_t)b * HID + t + 256] = a1;
  part[(size_t)b * HID + t + 512] = a2;
}

__global__ __launch_bounds__(256) void cls_head_kernel(
    const float* __restrict__ part, const int* __restrict__ amask,
    const float* __restrict__ clsW, const float* __restrict__ clsb,
    float* __restrict__ out) {
  __shared__ float pooled[HID];
  __shared__ float red[256];
  int t = threadIdx.x;
  for (int i = t; i < HID; i += 256) {
    float s = 0.f;
    for (int b2 = 0; b2 < 64; b2++) s += part[(size_t)b2 * HID + i];
    pooled[i] = s;
  }
  float c = 0.f;
  for (int s2 = t; s2 < S; s2 += 256) c += (float)amask[s2];
  float cnt = block_reduce_sum(c, red);
  float p0 = 0.f, p1 = 0.f;
  for (int i = t; i < HID; i += 256) {
    float pv = pooled[i] / cnt;
    p0 += pv * clsW[i * 2];
    p1 += pv * clsW[i * 2 + 1];
  }
  float s0 = block_reduce_sum(p0, red);
  float s1 = block_reduce_sum(p1, red);
  if (t == 0) { out[0] = s0 + clsb[0]; out[1] = s1 + clsb[1]; }
}

// ---------------- launch ----------------
extern "C" void kernel_launch(void* const* d_in, const int* in_sizes, int n_in,
                              void* d_out, int out_size, void* d_ws, size_t ws_size,
                              hipStream_t stream) {
  const int* ids = (const int*)d_in[0];
  const int* amask = (const int*)d_in[1];
  const int* gmask = (const int*)d_in[2];
  const float* tok = (const float*)d_in[3];
  const float* pos = (const float*)d_in[4];
  const float* elnw = (const float*)d_in[5];
  const float* elnb = (const float*)d_in[6];
  const float* Wqkv = (const float*)d_in[7];
  const float* bqkv = (const float*)d_in[8];
  const float* Wo = (const float*)d_in[9];
  const float* bo = (const float*)d_in[10];
  const float* ln1w = (const float*)d_in[11];
  const float* ln1b = (const float*)d_in[12];
  const float* W1 = (const float*)d_in[13];
  const float* b1 = (const float*)d_in[14];
  const float* W2 = (const float*)d_in[15];
  const float* b2 = (const float*)d_in[16];
  const float* ln2w = (const float*)d_in[17];
  const float* ln2b = (const float*)d_in[18];
  const float* clsW = (const float*)d_in[19];
  const float* clsb = (const float*)d_in[20];

  char* w8 = (char*)d_ws;
  size_t o = 0;
  f16* h16 = (f16*)(w8 + o); o += (size_t)S * HID * 2;
  f16* qkv16 = (f16*)(w8 + o); o += (size_t)S * QKV3 * 2;
  f16* attn16 = (f16*)(w8 + o); o += (size_t)S * HID * 2;
  f16* ff16 = (f16*)(w8 + o); o += (size_t)S * FF * 2;
  f16* sum16 = (f16*)(w8 + o); o += (size_t)S * HID * 2;
  float* part = (float*)(w8 + o); o += (size_t)64 * HID * 4;
  int* gidx = (int*)(w8 + o); o += 64;
  float* gvalid = (float*)(w8 + o); o += 64;
  f16* WqkvT = (f16*)(w8 + o); o += (size_t)NLAYER * HID * QKV3 * 2;
  f16* WoT = (f16*)(w8 + o); o += (size_t)NLAYER * HID * HID * 2;
  f16* W1T = (f16*)(w8 + o); o += (size_t)NLAYER * HID * FF * 2;
  f16* W2T = (f16*)(w8 + o); o += (size_t)NLAYER * FF * HID * 2;
  float* Sg = (float*)(w8 + o); o += (size_t)NH * NG * S * 4;
  float2* cstat = (float2*)(w8 + o); o += (size_t)NH * NG * 16 * 8;
  float* gpart = (float*)(w8 + o); o += (size_t)NH * NG * 16 * 64 * 4;

  gidx_kernel<<<1, 64, 0, stream>>>(gmask, gidx, gvalid);
  embed_ln_kernel<<<S, 256, 0, stream>>>(ids, tok, pos, elnw, elnb, h16);
  wt_kernel<<<dim3(QKV3 / 32, HID / 32, NLAYER), 256, 0, stream>>>(Wqkv, WqkvT, HID, QKV3);
  wt_kernel<<<dim3(HID / 32, HID / 32, NLAYER), 256, 0, stream>>>(Wo, WoT, HID, HID);
  wt_kernel<<<dim3(FF / 32, HID / 32, NLAYER), 256, 0, stream>>>(W1, W1T, HID, FF);
  wt_kernel<<<dim3(HID / 32, FF / 32, NLAYER), 256, 0, stream>>>(W2, W2T, FF, HID);

  for (int l = 0; l < NLAYER; l++) {
    gemm_f16_kernel<false><<<dim3(QKV3 / 128, S / 128), 256, 0, stream>>>(
        h16, WqkvT + (size_t)l * HID * QKV3, bqkv + (size_t)l * QKV3, qkv16, S, QKV3, HID);
    local_attn_mfma_kernel<<<NH * 64, 256, 0, stream>>>(
        qkv16, amask, gmask, gidx, gvalid, attn16);
    gscore_kernel<<<NH * 16, 256, 0, stream>>>(qkv16, amask, gidx, Sg, cstat);
    gpv_kernel<<<NH * 16, 256, 0, stream>>>(qkv16, Sg, cstat, gpart);
    gout_kernel<<<NH * NG, 64, 0, stream>>>(gpart, gidx, gvalid, attn16);
    gemm_f16_n64_kernel<true><<<dim3(HID / 64, S / 128), 256, 0, stream>>>(
        attn16, WoT + (size_t)l * HID * HID, bo + (size_t)l * HID, h16, sum16, S, HID, HID);
    ln_kernel<<<S, 256, 0, stream>>>(sum16, ln1w + (size_t)l * HID, ln1b + (size_t)l * HID, h16);
    gemm_f16_kernel<true><<<dim3(FF / 128, S / 128), 256, 0, stream>>>(
        h16, W1T + (size_t)l * HID * FF, b1 + (size_t)l * FF, ff16, S, FF, HID);
    gemm_f16_n64_kernel<true><<<dim3(HID / 64, S / 128), 256, 0, stream>>>(
        ff16, W2T + (size_t)l * FF * HID, b2 + (size_t)l * HID, h16, sum16, S, HID, FF);
    ln_kernel<<<S, 256, 0, stream>>>(sum16, ln2w + (size_t)l * HID, ln2b + (size_t)l * HID, h16);
  }
  pool_part_kernel<<<64, 256, 0, stream>>>(h16, amask, part);
  cls_head_kernel<<<1, 256, 0, stream>>>(part, amask, clsW, clsb, (float*)d_out);
}

// Round 10
// 2331.874 us; speedup vs baseline: 1.1576x; 1.0924x over previous
//
#include <hip/hip_runtime.h>
#include <cmath>

#define S 4096
#define HID 768
#define NH 12
#define DH 64
#define CHUNK 256
#define NC (S / CHUNK)
#define NG 16
#define FF 3072
#define NLAYER 12
#define QKV3 (3 * HID)
#define NEGV -1e9f

typedef _Float16 f16;
typedef __attribute__((ext_vector_type(2))) _Float16 f16x2;
typedef __attribute__((ext_vector_type(4))) _Float16 f16x4;
typedef __attribute__((ext_vector_type(8))) _Float16 f16x8;
typedef __attribute__((ext_vector_type(4))) float f32x4;

__device__ __forceinline__ void async16(f16* lds, const f16* g) {
  __builtin_amdgcn_global_load_lds((const __attribute__((address_space(1))) unsigned int*)g,
                                   (__attribute__((address_space(3))) unsigned int*)lds,
                                   16, 0, 0);
}

// bijective XCD swizzle for nwg % 8 == 0
__device__ __forceinline__ int xcd_swz(int lin, int nwg) {
  return (lin & 7) * (nwg >> 3) + (lin >> 3);
}

__device__ __forceinline__ float block_reduce_sum(float v, float* red) {
  int t = threadIdx.x;
  red[t] = v; __syncthreads();
  for (int st = 128; st > 0; st >>= 1) {
    if (t < st) red[t] += red[t + st];
    __syncthreads();
  }
  float r = red[0]; __syncthreads();
  return r;
}

// ---------------- gidx / gvalid (matches jax top_k semantics) ----------------
__global__ void gidx_kernel(const int* __restrict__ gmask, int* __restrict__ gidx,
                            float* __restrict__ gvalid) {
  if (threadIdx.x != 0 || blockIdx.x != 0) return;
  int cnt = 0;
  for (int s = 0; s < S && cnt < NG; s++)
    if (gmask[s] > 0) { gidx[cnt] = s; gvalid[cnt] = 1.f; cnt++; }
  for (int s = 0; s < S && cnt < NG; s++)
    if (gmask[s] == 0) { gidx[cnt] = s; gvalid[cnt] = 0.f; cnt++; }
}

// ---------------- embedding + LayerNorm (writes f16 residual stream) ----------------
__global__ __launch_bounds__(256) void embed_ln_kernel(
    const int* __restrict__ ids, const float* __restrict__ tok,
    const float* __restrict__ pos, const float* __restrict__ g,
    const float* __restrict__ b, f16* __restrict__ h16) {
  int s = blockIdx.x, t = threadIdx.x;
  __shared__ float xs[HID];
  __shared__ float red[256];
  const float* tr = tok + (size_t)ids[s] * HID;
  const float* pr = pos + (size_t)s * HID;
  float ls = 0.f;
  for (int i = t; i < HID; i += 256) { float v = tr[i] + pr[i]; xs[i] = v; ls += v; }
  float mu = block_reduce_sum(ls, red) * (1.f / HID);
  float lv = 0.f;
  for (int i = t; i < HID; i += 256) { float d = xs[i] - mu; lv += d * d; }
  float var = block_reduce_sum(lv, red) * (1.f / HID);
  float inv = rsqrtf(var + 1e-5f);
  for (int i = t; i < HID; i += 256)
    h16[(size_t)s * HID + i] = (f16)((xs[i] - mu) * inv * g[i] + b[i]);
}

// ---------------- LayerNorm: sum16 (pre-LN, f16) -> h16 ----------------
__global__ __launch_bounds__(256) void ln_kernel(
    const f16* __restrict__ sum16, const float* __restrict__ g,
    const float* __restrict__ b, f16* __restrict__ h16) {
  int s = blockIdx.x, t = threadIdx.x;
  __shared__ float red[256];
  float x0 = (float)sum16[(size_t)s * HID + t];
  float x1 = (float)sum16[(size_t)s * HID + t + 256];
  float x2 = (float)sum16[(size_t)s * HID + t + 512];
  float mu = block_reduce_sum(x0 + x1 + x2, red) * (1.f / HID);
  float d0 = x0 - mu, d1 = x1 - mu, d2 = x2 - mu;
  float var = block_reduce_sum(d0 * d0 + d1 * d1 + d2 * d2, red) * (1.f / HID);
  float inv = rsqrtf(var + 1e-5f);
  h16[(size_t)s * HID + t] = (f16)(d0 * inv * g[t] + b[t]);
  h16[(size_t)s * HID + t + 256] = (f16)(d1 * inv * g[t + 256] + b[t + 256]);
  h16[(size_t)s * HID + t + 512] = (f16)(d2 * inv * g[t + 512] + b[t + 512]);
}

// ---- LayerNorm for split-K FFN2: x = p0 + p1 + bias + resid(h16); LN -> h16 ----
__global__ __launch_bounds__(256) void ln_ffn2_kernel(
    const f16* __restrict__ p0, const f16* __restrict__ p1,
    const float* __restrict__ bias, const float* __restrict__ g,
    const float* __restrict__ b, f16* __restrict__ h16) {
  int s = blockIdx.x, t = threadIdx.x;
  __shared__ float red[256];
  size_t base = (size_t)s * HID;
  float x0 = (float)p0[base + t] + (float)p1[base + t] + bias[t] + (float)h16[base + t];
  float x1 = (float)p0[base + t + 256] + (float)p1[base + t + 256] + bias[t + 256] +
             (float)h16[base + t + 256];
  float x2 = (float)p0[base + t + 512] + (float)p1[base + t + 512] + bias[t + 512] +
             (float)h16[base + t + 512];
  float mu = block_reduce_sum(x0 + x1 + x2, red) * (1.f / HID);
  float d0 = x0 - mu, d1 = x1 - mu, d2 = x2 - mu;
  float var = block_reduce_sum(d0 * d0 + d1 * d1 + d2 * d2, red) * (1.f / HID);
  float inv = rsqrtf(var + 1e-5f);
  h16[base + t] = (f16)(d0 * inv * g[t] + b[t]);
  h16[base + t + 256] = (f16)(d1 * inv * g[t + 256] + b[t + 256]);
  h16[base + t + 512] = (f16)(d2 * inv * g[t + 512] + b[t + 512]);
}

// ------ weight transpose + f16 convert, ALL layers: W[l][K][N] f32 -> WT[l][N][K] f16
__global__ __launch_bounds__(256) void wt_kernel(const float* __restrict__ W,
                                                 f16* __restrict__ WT, int K, int N) {
  size_t lo = (size_t)blockIdx.z * K * N;
  const float* Wl = W + lo;
  f16* WTl = WT + lo;
  __shared__ float tile[32][33];
  int k0 = blockIdx.y * 32, n0 = blockIdx.x * 32;
  int t = threadIdx.x;
  int r = t >> 3, c = (t & 7) * 4;
  float4 v = *(const float4*)&Wl[(size_t)(k0 + r) * N + n0 + c];
  tile[r][c] = v.x; tile[r][c + 1] = v.y; tile[r][c + 2] = v.z; tile[r][c + 3] = v.w;
  __syncthreads();
  int n = t >> 3, kq = (t & 7) * 4;
  f16x4 o = {(f16)tile[kq][n], (f16)tile[kq + 1][n], (f16)tile[kq + 2][n], (f16)tile[kq + 3][n]};
  *(f16x4*)&WTl[(size_t)(n0 + n) * K + k0 + kq] = o;
}

// ---- fp16 MFMA GEMM 128x128, single-buffer 2-barrier (proven structure) ----
#define GBK 64

template <bool GELU>
__global__ __launch_bounds__(256) void gemm_f16_kernel(
    const f16* __restrict__ A, const f16* __restrict__ BT,
    const float* __restrict__ bias, f16* __restrict__ Cout, int M, int N, int K) {
  __shared__ f16 As[128 * GBK];
  __shared__ f16 Bs[128 * GBK];
  int t = threadIdx.x, lane = t & 63, wave = t >> 6;
  int wr = wave >> 1, wc = wave & 1;
  int gx = gridDim.x;
  int nl = xcd_swz(blockIdx.y * gx + blockIdx.x, gx * gridDim.y);
  int bx = nl % gx, by = nl / gx;

  f32x4 acc[4][4];
#pragma unroll
  for (int mi = 0; mi < 4; mi++)
#pragma unroll
    for (int ni = 0; ni < 4; ni++) acc[mi][ni] = (f32x4){0.f, 0.f, 0.f, 0.f};

  const f16* Ablk = A + (size_t)(by * 128) * K;
  const f16* Bblk = BT + (size_t)(bx * 128) * K;
  int rl = lane >> 3;
  int lc = (lane & 7) ^ rl;

  for (int k0 = 0; k0 < K; k0 += GBK) {
#pragma unroll
    for (int ii = 0; ii < 4; ii++) {
      int i = wave * 4 + ii;
      int r = i * 8 + rl;
      async16(&As[i * 512], Ablk + (size_t)r * K + k0 + lc * 8);
      async16(&Bs[i * 512], Bblk + (size_t)r * K + k0 + lc * 8);
    }
    __syncthreads();
#pragma unroll
    for (int kc = 0; kc < 2; kc++) {
      f16x8 af[4], bf[4];
#pragma unroll
      for (int mi = 0; mi < 4; mi++) {
        int row = wr * 64 + mi * 16 + (lane & 15);
        int pc = (kc * 4 + (lane >> 4)) ^ (row & 7);
        af[mi] = *(const f16x8*)&As[row * 64 + pc * 8];
      }
#pragma unroll
      for (int ni = 0; ni < 4; ni++) {
        int row = wc * 64 + ni * 16 + (lane & 15);
        int pc = (kc * 4 + (lane >> 4)) ^ (row & 7);
        bf[ni] = *(const f16x8*)&Bs[row * 64 + pc * 8];
      }
#pragma unroll
      for (int mi = 0; mi < 4; mi++)
#pragma unroll
        for (int ni = 0; ni < 4; ni++)
          acc[mi][ni] = __builtin_amdgcn_mfma_f32_16x16x32_f16(af[mi], bf[ni], acc[mi][ni], 0, 0, 0);
    }
    __syncthreads();
  }

  int row_base = by * 128 + wr * 64 + (lane >> 4) * 4;
  int col_base = bx * 128 + wc * 64 + (lane & 15);
#pragma unroll
  for (int mi = 0; mi < 4; mi++) {
#pragma unroll
    for (int ni = 0; ni < 4; ni++) {
      int col = col_base + ni * 16;
      float bs = bias[col];
#pragma unroll
      for (int j = 0; j < 4; j++) {
        int row = row_base + mi * 16 + j;
        float x = acc[mi][ni][j] + bs;
        if (GELU) x = 0.5f * x * (1.f + erff(x * 0.70710678118654752f));
        Cout[(size_t)row * N + col] = (f16)x;
      }
    }
  }
}

// ---- fp16 MFMA GEMM 128x64 (N=768 outputs), fused residual add ----
template <bool RESID>
__global__ __launch_bounds__(256) void gemm_f16_n64_kernel(
    const f16* __restrict__ A, const f16* __restrict__ BT,
    const float* __restrict__ bias, const f16* __restrict__ resid,
    f16* __restrict__ Cout, int M, int N, int K) {
  __shared__ f16 As[128 * GBK];
  __shared__ f16 Bs[64 * GBK];
  int t = threadIdx.x, lane = t & 63, wave = t >> 6;
  int wr = wave >> 1, wc = wave & 1;
  int gx = gridDim.x;
  int nl = xcd_swz(blockIdx.y * gx + blockIdx.x, gx * gridDim.y);
  int bx = nl % gx, by = nl / gx;

  f32x4 acc[4][2];
#pragma unroll
  for (int mi = 0; mi < 4; mi++)
#pragma unroll
    for (int ni = 0; ni < 2; ni++) acc[mi][ni] = (f32x4){0.f, 0.f, 0.f, 0.f};

  const f16* Ablk = A + (size_t)(by * 128) * K;
  const f16* Bblk = BT + (size_t)(bx * 64) * K;
  int rl = lane >> 3;
  int lc = (lane & 7) ^ rl;

  for (int k0 = 0; k0 < K; k0 += GBK) {
#pragma unroll
    for (int ii = 0; ii < 4; ii++) {
      int i = wave * 4 + ii;
      int r = i * 8 + rl;
      async16(&As[i * 512], Ablk + (size_t)r * K + k0 + lc * 8);
    }
#pragma unroll
    for (int ii = 0; ii < 2; ii++) {
      int i = wave * 2 + ii;
      int r = i * 8 + rl;
      async16(&Bs[i * 512], Bblk + (size_t)r * K + k0 + lc * 8);
    }
    __syncthreads();
#pragma unroll
    for (int kc = 0; kc < 2; kc++) {
      f16x8 af[4], bf[2];
#pragma unroll
      for (int mi = 0; mi < 4; mi++) {
        int row = wr * 64 + mi * 16 + (lane & 15);
        int pc = (kc * 4 + (lane >> 4)) ^ (row & 7);
        af[mi] = *(const f16x8*)&As[row * 64 + pc * 8];
      }
#pragma unroll
      for (int ni = 0; ni < 2; ni++) {
        int row = wc * 32 + ni * 16 + (lane & 15);
        int pc = (kc * 4 + (lane >> 4)) ^ (row & 7);
        bf[ni] = *(const f16x8*)&Bs[row * 64 + pc * 8];
      }
#pragma unroll
      for (int mi = 0; mi < 4; mi++)
#pragma unroll
        for (int ni = 0; ni < 2; ni++)
          acc[mi][ni] = __builtin_amdgcn_mfma_f32_16x16x32_f16(af[mi], bf[ni], acc[mi][ni], 0, 0, 0);
    }
    __syncthreads();
  }

  int row_base = by * 128 + wr * 64 + (lane >> 4) * 4;
  int col_base = bx * 64 + wc * 32 + (lane & 15);
#pragma unroll
  for (int mi = 0; mi < 4; mi++) {
#pragma unroll
    for (int ni = 0; ni < 2; ni++) {
      int col = col_base + ni * 16;
      float bs = bias[col];
#pragma unroll
      for (int j = 0; j < 4; j++) {
        int row = row_base + mi * 16 + j;
        float x = acc[mi][ni][j] + bs;
        if (RESID) x += (float)resid[(size_t)row * N + col];
        Cout[(size_t)row * N + col] = (f16)x;
      }
    }
  }
}

// ---- fp16 MFMA GEMM 128x64 split-K (z = 0/1): raw f16 partials, no bias ----
__global__ __launch_bounds__(256) void gemm_f16_n64_splitk_kernel(
    const f16* __restrict__ A, const f16* __restrict__ BT,
    f16* __restrict__ p0, f16* __restrict__ p1, int M, int N, int K) {
  __shared__ f16 As[128 * GBK];
  __shared__ f16 Bs[64 * GBK];
  int t = threadIdx.x, lane = t & 63, wave = t >> 6;
  int wr = wave >> 1, wc = wave & 1;
  int gx = gridDim.x;
  int nl = xcd_swz(blockIdx.y * gx + blockIdx.x, gx * gridDim.y);
  int bx = nl % gx, by = nl / gx;
  int kz = blockIdx.z;
  int KH = K >> 1;
  f16* pout = kz ? p1 : p0;

  f32x4 acc[4][2];
#pragma unroll
  for (int mi = 0; mi < 4; mi++)
#pragma unroll
    for (int ni = 0; ni < 2; ni++) acc[mi][ni] = (f32x4){0.f, 0.f, 0.f, 0.f};

  const f16* Ablk = A + (size_t)(by * 128) * K + (size_t)kz * KH;
  const f16* Bblk = BT + (size_t)(bx * 64) * K + (size_t)kz * KH;
  int rl = lane >> 3;
  int lc = (lane & 7) ^ rl;

  for (int k0 = 0; k0 < KH; k0 += GBK) {
#pragma unroll
    for (int ii = 0; ii < 4; ii++) {
      int i = wave * 4 + ii;
      int r = i * 8 + rl;
      async16(&As[i * 512], Ablk + (size_t)r * K + k0 + lc * 8);
    }
#pragma unroll
    for (int ii = 0; ii < 2; ii++) {
      int i = wave * 2 + ii;
      int r = i * 8 + rl;
      async16(&Bs[i * 512], Bblk + (size_t)r * K + k0 + lc * 8);
    }
    __syncthreads();
#pragma unroll
    for (int kc = 0; kc < 2; kc++) {
      f16x8 af[4], bf[2];
#pragma unroll
      for (int mi = 0; mi < 4; mi++) {
        int row = wr * 64 + mi * 16 + (lane & 15);
        int pc = (kc * 4 + (lane >> 4)) ^ (row & 7);
        af[mi] = *(const f16x8*)&As[row * 64 + pc * 8];
      }
#pragma unroll
      for (int ni = 0; ni < 2; ni++) {
        int row = wc * 32 + ni * 16 + (lane & 15);
        int pc = (kc * 4 + (lane >> 4)) ^ (row & 7);
        bf[ni] = *(const f16x8*)&Bs[row * 64 + pc * 8];
      }
#pragma unroll
      for (int mi = 0; mi < 4; mi++)
#pragma unroll
        for (int ni = 0; ni < 2; ni++)
          acc[mi][ni] = __builtin_amdgcn_mfma_f32_16x16x32_f16(af[mi], bf[ni], acc[mi][ni], 0, 0, 0);
    }
    __syncthreads();
  }

  int row_base = by * 128 + wr * 64 + (lane >> 4) * 4;
  int col_base = bx * 64 + wc * 32 + (lane & 15);
#pragma unroll
  for (int mi = 0; mi < 4; mi++) {
#pragma unroll
    for (int ni = 0; ni < 2; ni++) {
      int col = col_base + ni * 16;
#pragma unroll
      for (int j = 0; j < 4; j++) {
        int row = row_base + mi * 16 + j;
        pout[(size_t)row * N + col] = (f16)acc[mi][ni][j];
      }
    }
  }
}

// ---------------- MFMA local windowed attention, T14 async-stage prefetch ----------------
#define ROWP 72  // padded LDS row: 64 halves + 8 pad (144B)

__device__ __forceinline__ void pf_load(
    const f16* __restrict__ qkv, const int* __restrict__ gidx, const float* gvs,
    int h, int q0, int kt, int t,
    f16x8& pk0, f16x8& pk1, f16x8& pva, f16x8& pvb) {
  int jb = q0 - 256 + kt * 64;
  bool isG = (kt == 9);
  pk0 = (f16x8){}; pk1 = (f16x8){}; pva = (f16x8){}; pvb = (f16x8){};
  // K: row kr, 16 halves at c2*8
  int kr = t >> 2, c2 = (t & 3) * 2;
  bool kok_;
  int jk;
  if (isG) { kok_ = (kr < NG) && (gvs[kr] > 0.f); jk = kok_ ? gidx[kr] : 0; }
  else { kok_ = true; jk = jb + kr; }  // valid local tiles are fully in-range
  if (kok_) {
    const f16* kp = qkv + (size_t)jk * QKV3 + HID + h * DH + c2 * 8;
    pk0 = *(const f16x8*)kp;
    pk1 = *(const f16x8*)(kp + 8);
  }
  // V: key pair (k2, k2+1), d-range dq..dq+7
  int k2 = (t & 31) * 2, dq = (t >> 5) * 8;
  bool o0, o1;
  int j0, j1;
  if (isG) {
    o0 = (k2 < NG) && (gvs[k2] > 0.f); j0 = o0 ? gidx[k2] : 0;
    o1 = (k2 + 1 < NG) && (gvs[k2 + 1] > 0.f); j1 = o1 ? gidx[k2 + 1] : 0;
  } else { o0 = o1 = true; j0 = jb + k2; j1 = jb + k2 + 1; }
  if (o0) pva = *(const f16x8*)(qkv + (size_t)j0 * QKV3 + 2 * HID + h * DH + dq);
  if (o1) pvb = *(const f16x8*)(qkv + (size_t)j1 * QKV3 + 2 * HID + h * DH + dq);
}

__global__ __launch_bounds__(256) void local_attn_mfma_kernel(
    const f16* __restrict__ qkv, const int* __restrict__ amask,
    const int* __restrict__ gmask, const int* __restrict__ gidx,
    const float* __restrict__ gvalid, f16* __restrict__ outp) {
  int nl = xcd_swz(blockIdx.x, NH * 64);
  int h = nl >> 6;
  int qb = nl & 63;
  int q0 = qb * 64;
  int t = threadIdx.x, lane = t & 63, w = t >> 6;
  int g4 = lane >> 4, l15 = lane & 15;

  __shared__ f16 Qs[64 * ROWP];
  __shared__ f16 Kt[64 * ROWP];
  __shared__ f16 Vt[64 * ROWP];
  __shared__ f16 Pb[4 * 16 * ROWP];
  __shared__ unsigned kokLo, kokHi;
  __shared__ float gvs[NG];

  {  // stage Q (scaled by 1/8)
    int r = t >> 2, c2 = (t & 3) * 2;
    const f16* qr = qkv + (size_t)(q0 + r) * QKV3 + h * DH + c2 * 8;
    f16x8 v0 = *(const f16x8*)qr;
    f16x8 v1 = *(const f16x8*)(qr + 8);
#pragma unroll
    for (int e = 0; e < 8; e++) { v0[e] = v0[e] * (f16)0.125f; v1[e] = v1[e] * (f16)0.125f; }
    *(f16x8*)&Qs[r * ROWP + c2 * 8] = v0;
    *(f16x8*)&Qs[r * ROWP + c2 * 8 + 8] = v1;
    if (t < NG) gvs[t] = gvalid[t];
  }
  __syncthreads();

  int qrow = w * 16 + l15;
  f16x8 qf0 = *(const f16x8*)&Qs[qrow * ROWP + g4 * 8];
  f16x8 qf1 = *(const f16x8*)&Qs[qrow * ROWP + 32 + g4 * 8];

  float mb = -50000.f, lp = 0.f;
  f32x4 oacc[4];
#pragma unroll
  for (int sd = 0; sd < 4; sd++) oacc[sd] = (f32x4){0.f, 0.f, 0.f, 0.f};

  f16* Pw = &Pb[w * 16 * ROWP];

  // valid local tiles: kt in [kt_lo, kt_hi]; then global tile (kt=9)
  int kt_lo = q0 >= 256 ? 0 : (256 - q0) >> 6;
  int kt_hi = (4288 - q0) >> 6;
  if (kt_hi > 8) kt_hi = 8;
  int ntile = kt_hi - kt_lo + 2;

  f16x8 pk0, pk1, pva, pvb;
  pf_load(qkv, gidx, gvs, h, q0, kt_lo, t, pk0, pk1, pva, pvb);

  for (int it = 0; it < ntile; it++) {
    int kt = (it < ntile - 1) ? kt_lo + it : 9;
    int jb = q0 - 256 + kt * 64;
    bool isG = (kt == 9);
    __syncthreads();  // previous compute done reading LDS
    {  // write prefetched K [k][d]
      int kr = t >> 2, c2 = (t & 3) * 2;
      *(f16x8*)&Kt[kr * ROWP + c2 * 8] = pk0;
      *(f16x8*)&Kt[kr * ROWP + c2 * 8 + 8] = pk1;
    }
    {  // write prefetched V transposed [d][k]
      int k2 = (t & 31) * 2, dq = (t >> 5) * 8;
#pragma unroll
      for (int e = 0; e < 8; e++) {
        f16x2 pr = {pva[e], pvb[e]};
        *(f16x2*)&Vt[(dq + e) * ROWP + k2] = pr;
      }
    }
    if (w == 0) {  // key-ok bitmask for tile kt
      int k = lane;
      bool ok;
      if (isG) ok = (k < NG && gvs[k] > 0.f);
      else {
        int j = jb + k;
        ok = (amask[j] != 0) && (gmask[j] == 0);
      }
      unsigned long long m = __ballot(ok);
      if (lane == 0) { kokLo = (unsigned)m; kokHi = (unsigned)(m >> 32); }
    }
    if (it + 1 < ntile) {  // T14: issue next tile's loads; land during compute
      int ktn = (it + 1 < ntile - 1) ? kt_lo + it + 1 : 9;
      pf_load(qkv, gidx, gvs, h, q0, ktn, t, pk0, pk1, pva, pvb);
    }
    __syncthreads();  // staging visible

    unsigned long long kok = ((unsigned long long)kokHi << 32) | (unsigned long long)kokLo;

    f32x4 sv[4];
    __builtin_amdgcn_s_setprio(1);
#pragma unroll
    for (int s4 = 0; s4 < 4; s4++) {
      int krow = s4 * 16 + l15;
      f16x8 ka0 = *(const f16x8*)&Kt[krow * ROWP + g4 * 8];
      f16x8 ka1 = *(const f16x8*)&Kt[krow * ROWP + 32 + g4 * 8];
      f32x4 a = {0.f, 0.f, 0.f, 0.f};
      a = __builtin_amdgcn_mfma_f32_16x16x32_f16(ka0, qf0, a, 0, 0, 0);
      a = __builtin_amdgcn_mfma_f32_16x16x32_f16(ka1, qf1, a, 0, 0, 0);
      sv[s4] = a;
    }
    __builtin_amdgcn_s_setprio(0);
    int ql = w * 16 + l15;
#pragma unroll
    for (int s4 = 0; s4 < 4; s4++)
#pragma unroll
      for (int r = 0; r < 4; r++) {
        int kl = s4 * 16 + g4 * 4 + r;
        bool ok = (kok >> kl) & 1ull;
        if (kt == 0) ok = ok && (kl >= ql);
        else if (kt == 8) ok = ok && (kl <= ql);
        sv[s4][r] = ok ? sv[s4][r] : -1e30f;
      }
    float mt = -1e30f;
#pragma unroll
    for (int s4 = 0; s4 < 4; s4++)
#pragma unroll
      for (int r = 0; r < 4; r++) mt = fmaxf(mt, sv[s4][r]);
    mt = fmaxf(mt, __shfl_xor(mt, 16));
    mt = fmaxf(mt, __shfl_xor(mt, 32));
    float mn = fmaxf(mb, mt);
    float corr = __expf(mb - mn);
    mb = mn;
    lp *= corr;
#pragma unroll
    for (int sd = 0; sd < 4; sd++)
#pragma unroll
      for (int r = 0; r < 4; r++) oacc[sd][r] *= corr;
#pragma unroll
    for (int s4 = 0; s4 < 4; s4++) {
#pragma unroll
      for (int rp = 0; rp < 2; rp++) {
        float p0 = __expf(sv[s4][rp * 2] - mn);
        float p1 = __expf(sv[s4][rp * 2 + 1] - mn);
        f16 h0 = (f16)p0, h1 = (f16)p1;
        lp += (float)h0 + (float)h1;
        int kl = s4 * 16 + g4 * 4 + rp * 2;
        f16x2 pr = {h0, h1};
        *(f16x2*)&Pw[l15 * ROWP + kl] = pr;
      }
    }
    f16x8 pf0 = *(const f16x8*)&Pw[l15 * ROWP + g4 * 8];
    f16x8 pf1 = *(const f16x8*)&Pw[l15 * ROWP + 32 + g4 * 8];
    __builtin_amdgcn_s_setprio(1);
#pragma unroll
    for (int sd = 0; sd < 4; sd++) {
      int drow = sd * 16 + l15;
      f16x8 va0 = *(const f16x8*)&Vt[drow * ROWP + g4 * 8];
      f16x8 va1 = *(const f16x8*)&Vt[drow * ROWP + 32 + g4 * 8];
      oacc[sd] = __builtin_amdgcn_mfma_f32_16x16x32_f16(va0, pf0, oacc[sd], 0, 0, 0);
      oacc[sd] = __builtin_amdgcn_mfma_f32_16x16x32_f16(va1, pf1, oacc[sd], 0, 0, 0);
    }
    __builtin_amdgcn_s_setprio(0);
  }

  float lt = lp + __shfl_xor(lp, 16);
  lt = lt + __shfl_xor(lt, 32);
  float inv = (lt > 0.f) ? 1.f / lt : 0.f;
  int qg = q0 + w * 16 + l15;
  f16* orow = outp + (size_t)qg * HID + h * DH;
#pragma unroll
  for (int sd = 0; sd < 4; sd++)
#pragma unroll
    for (int r = 0; r < 4; r++)
      orow[sd * 16 + g4 * 4 + r] = (f16)(oacc[sd][r] * inv);
}

// ============ global-token attention, split-K pipeline ============
__global__ __launch_bounds__(256) void gscore_kernel(
    const f16* __restrict__ qkv, const int* __restrict__ amask,
    const int* __restrict__ gidx, float* __restrict__ Sg, float2* __restrict__ cstat) {
  int h = blockIdx.x >> 4, jc = blockIdx.x & 15;
  int t = threadIdx.x, lane = t & 63, w = t >> 6;
  __shared__ f16 Qs[NG][DH];
  __shared__ float wred[4][NG];
  __shared__ float cmaxs[NG];
  if (t < 128) {
    int g = t >> 3, c = (t & 7) * 8;
    const f16* qr = qkv + (size_t)gidx[g] * QKV3 + h * DH + c;
    *(f16x8*)&Qs[g][c] = *(const f16x8*)qr;
  }
  __syncthreads();
  int j = jc * 256 + t;
  const f16x8* kr = (const f16x8*)(qkv + (size_t)j * QKV3 + HID + h * DH);
  f16x8 kv[8];
#pragma unroll
  for (int c = 0; c < 8; c++) kv[c] = kr[c];
  bool ok = amask[j] != 0;
  float sg[NG];
#pragma unroll 4
  for (int g = 0; g < NG; g++) {
    float s = 0.f;
#pragma unroll
    for (int c = 0; c < 8; c++) {
      f16x8 qv = *(const f16x8*)&Qs[g][c * 8];
#pragma unroll
      for (int e = 0; e < 8; e++) s += (float)qv[e] * (float)kv[c][e];
    }
    sg[g] = ok ? s * 0.125f : NEGV;
    Sg[(size_t)(h * NG + g) * S + j] = sg[g];
  }
#pragma unroll
  for (int g = 0; g < NG; g++) {
    float m = sg[g];
#pragma unroll
    for (int st = 1; st < 64; st <<= 1) m = fmaxf(m, __shfl_xor(m, st));
    if (lane == 0) wred[w][g] = m;
  }
  __syncthreads();
  if (t < NG)
    cmaxs[t] = fmaxf(fmaxf(wred[0][t], wred[1][t]), fmaxf(wred[2][t], wred[3][t]));
  __syncthreads();
#pragma unroll
  for (int g = 0; g < NG; g++) {
    float p = __expf(sg[g] - cmaxs[g]);
#pragma unroll
    for (int st = 1; st < 64; st <<= 1) p += __shfl_xor(p, st);
    if (lane == 0) wred[w][g] = p;
  }
  __syncthreads();
  if (t < NG) {
    float s4 = wred[0][t] + wred[1][t] + wred[2][t] + wred[3][t];
    cstat[((size_t)(h * NG + t)) * 16 + jc] = make_float2(cmaxs[t], s4);
  }
}

__global__ __launch_bounds__(256) void gpv_kernel(
    const f16* __restrict__ qkv, const float* __restrict__ Sg,
    const float2* __restrict__ cstat, float* __restrict__ part) {
  int h = blockIdx.x >> 4, jc = blockIdx.x & 15;
  int jb = jc * 256;
  int t = threadIdx.x;
  __shared__ float Ps[NG][256];
  __shared__ f16 Vs[256][DH];
  __shared__ float ms[NG], dinv[NG];
  if (t < NG) {
    const float2* cs = &cstat[((size_t)(h * NG + t)) * 16];
    float m = -1e30f;
#pragma unroll
    for (int c = 0; c < 16; c++) m = fmaxf(m, cs[c].x);
    float den = 0.f;
#pragma unroll
    for (int c = 0; c < 16; c++) den += cs[c].y * __expf(cs[c].x - m);
    ms[t] = m;
    dinv[t] = den > 0.f ? 1.f / den : 0.f;
  }
  __syncthreads();
#pragma unroll
  for (int g = 0; g < NG; g++)
    Ps[g][t] = __expf(Sg[(size_t)(h * NG + g) * S + jb + t] - ms[g]) * dinv[g];
  {
    int r = t >> 3, c = (t & 7) * 8;
#pragma unroll
    for (int pp = 0; pp < 8; pp++) {
      int row = pp * 32 + r;
      const f16* vr = qkv + (size_t)(jb + row) * QKV3 + 2 * HID + h * DH + c;
      *(f16x8*)&Vs[row][c] = *(const f16x8*)vr;
    }
  }
  __syncthreads();
  int d = t & 63, g4 = t >> 6;
  float o0 = 0.f, o1 = 0.f, o2 = 0.f, o3 = 0.f;
#pragma unroll 8
  for (int j = 0; j < 256; j++) {
    float v = (float)Vs[j][d];
    o0 += Ps[g4][j] * v;
    o1 += Ps[g4 + 4][j] * v;
    o2 += Ps[g4 + 8][j] * v;
    o3 += Ps[g4 + 12][j] * v;
  }
  size_t base = ((size_t)h * NG) * 16 * 64;
  part[base + ((size_t)(g4) * 16 + jc) * 64 + d] = o0;
  part[base + ((size_t)(g4 + 4) * 16 + jc) * 64 + d] = o1;
  part[base + ((size_t)(g4 + 8) * 16 + jc) * 64 + d] = o2;
  part[base + ((size_t)(g4 + 12) * 16 + jc) * 64 + d] = o3;
}

__global__ __launch_bounds__(64) void gout_kernel(
    const float* __restrict__ part, const int* __restrict__ gidx,
    const float* __restrict__ gvalid, f16* __restrict__ attn16) {
  int h = blockIdx.x >> 4, g = blockIdx.x & 15;
  if (gvalid[g] <= 0.f) return;
  int d = threadIdx.x;
  const float* pr = part + (((size_t)(h * NG + g)) * 16) * 64 + d;
  float s = 0.f;
#pragma unroll
  for (int jc = 0; jc < 16; jc++) s += pr[jc * 64];
  attn16[(size_t)gidx[g] * HID + h * DH + d] = (f16)s;
}

// ---------------- masked mean pool (partials) + classifier head ----------------
__global__ __launch_bounds__(256) void pool_part_kernel(
    const f16* __restrict__ h, const int* __restrict__ amask, float* __restrict__ part) {
  int b = blockIdx.x, t = threadIdx.x;
  float a0 = 0.f, a1 = 0.f, a2 = 0.f;
  for (int r = 0; r < 64; r++) {
    int s = b * 64 + r;
    float w = (float)amask[s];
    const f16* hr = h + (size_t)s * HID;
    a0 += (float)hr[t] * w;
    a1 += (float)hr[t + 256] * w;
    a2 += (float)hr[t + 512] * w;
  }
  part[(size_t)b * HID + t] = a0;
  part[(size_t)b * HID + t + 256] = a1;
  part[(size_t)b * HID + t + 512] = a2;
}

__global__ __launch_bounds__(256) void cls_head_kernel(
    const float* __restrict__ part, const int* __restrict__ amask,
    const float* __restrict__ clsW, const float* __restrict__ clsb,
    float* __restrict__ out) {
  __shared__ float pooled[HID];
  __shared__ float red[256];
  int t = threadIdx.x;
  for (int i = t; i < HID; i += 256) {
    float s = 0.f;
    for (int b2 = 0; b2 < 64; b2++) s += part[(size_t)b2 * HID + i];
    pooled[i] = s;
  }
  float c = 0.f;
  for (int s2 = t; s2 < S; s2 += 256) c += (float)amask[s2];
  float cnt = block_reduce_sum(c, red);
  float p0 = 0.f, p1 = 0.f;
  for (int i = t; i < HID; i += 256) {
    float pv = pooled[i] / cnt;
    p0 += pv * clsW[i * 2];
    p1 += pv * clsW[i * 2 + 1];
  }
  float s0 = block_reduce_sum(p0, red);
  float s1 = block_reduce_sum(p1, red);
  if (t == 0) { out[0] = s0 + clsb[0]; out[1] = s1 + clsb[1]; }
}

// ---------------- launch ----------------
extern "C" void kernel_launch(void* const* d_in, const int* in_sizes, int n_in,
                              void* d_out, int out_size, void* d_ws, size_t ws_size,
                              hipStream_t stream) {
  const int* ids = (const int*)d_in[0];
  const int* amask = (const int*)d_in[1];
  const int* gmask = (const int*)d_in[2];
  const float* tok = (const float*)d_in[3];
  const float* pos = (const float*)d_in[4];
  const float* elnw = (const float*)d_in[5];
  const float* elnb = (const float*)d_in[6];
  const float* Wqkv = (const float*)d_in[7];
  const float* bqkv = (const float*)d_in[8];
  const float* Wo = (const float*)d_in[9];
  const float* bo = (const float*)d_in[10];
  const float* ln1w = (const float*)d_in[11];
  const float* ln1b = (const float*)d_in[12];
  const float* W1 = (const float*)d_in[13];
  const float* b1 = (const float*)d_in[14];
  const float* W2 = (const float*)d_in[15];
  const float* b2 = (const float*)d_in[16];
  const float* ln2w = (const float*)d_in[17];
  const float* ln2b = (const float*)d_in[18];
  const float* clsW = (const float*)d_in[19];
  const float* clsb = (const float*)d_in[20];

  char* w8 = (char*)d_ws;
  size_t o = 0;
  f16* h16 = (f16*)(w8 + o); o += (size_t)S * HID * 2;
  f16* qkv16 = (f16*)(w8 + o); o += (size_t)S * QKV3 * 2;
  f16* attn16 = (f16*)(w8 + o); o += (size_t)S * HID * 2;
  f16* ff16 = (f16*)(w8 + o); o += (size_t)S * FF * 2;
  f16* sum16 = (f16*)(w8 + o); o += (size_t)S * HID * 2;  // also split-K p0
  f16* p1 = (f16*)(w8 + o); o += (size_t)S * HID * 2;     // split-K p1
  float* part = (float*)(w8 + o); o += (size_t)64 * HID * 4;
  int* gidx = (int*)(w8 + o); o += 64;
  float* gvalid = (float*)(w8 + o); o += 64;
  f16* WqkvT = (f16*)(w8 + o); o += (size_t)NLAYER * HID * QKV3 * 2;
  f16* WoT = (f16*)(w8 + o); o += (size_t)NLAYER * HID * HID * 2;
  f16* W1T = (f16*)(w8 + o); o += (size_t)NLAYER * HID * FF * 2;
  f16* W2T = (f16*)(w8 + o); o += (size_t)NLAYER * FF * HID * 2;
  float* Sg = (float*)(w8 + o); o += (size_t)NH * NG * S * 4;
  float2* cstat = (float2*)(w8 + o); o += (size_t)NH * NG * 16 * 8;
  float* gpart = (float*)(w8 + o); o += (size_t)NH * NG * 16 * 64 * 4;

  gidx_kernel<<<1, 64, 0, stream>>>(gmask, gidx, gvalid);
  embed_ln_kernel<<<S, 256, 0, stream>>>(ids, tok, pos, elnw, elnb, h16);
  wt_kernel<<<dim3(QKV3 / 32, HID / 32, NLAYER), 256, 0, stream>>>(Wqkv, WqkvT, HID, QKV3);
  wt_kernel<<<dim3(HID / 32, HID / 32, NLAYER), 256, 0, stream>>>(Wo, WoT, HID, HID);
  wt_kernel<<<dim3(FF / 32, HID / 32, NLAYER), 256, 0, stream>>>(W1, W1T, HID, FF);
  wt_kernel<<<dim3(HID / 32, FF / 32, NLAYER), 256, 0, stream>>>(W2, W2T, FF, HID);

  for (int l = 0; l < NLAYER; l++) {
    gemm_f16_kernel<false><<<dim3(QKV3 / 128, S / 128), 256, 0, stream>>>(
        h16, WqkvT + (size_t)l * HID * QKV3, bqkv + (size_t)l * QKV3, qkv16, S, QKV3, HID);
    local_attn_mfma_kernel<<<NH * 64, 256, 0, stream>>>(
        qkv16, amask, gmask, gidx, gvalid, attn16);
    gscore_kernel<<<NH * 16, 256, 0, stream>>>(qkv16, amask, gidx, Sg, cstat);
    gpv_kernel<<<NH * 16, 256, 0, stream>>>(qkv16, Sg, cstat, gpart);
    gout_kernel<<<NH * NG, 64, 0, stream>>>(gpart, gidx, gvalid, attn16);
    gemm_f16_n64_kernel<true><<<dim3(HID / 64, S / 128), 256, 0, stream>>>(
        attn16, WoT + (size_t)l * HID * HID, bo + (size_t)l * HID, h16, sum16, S, HID, HID);
    ln_kernel<<<S, 256, 0, stream>>>(sum16, ln1w + (size_t)l * HID, ln1b + (size_t)l * HID, h16);
    gemm_f16_kernel<true><<<dim3(FF / 128, S / 128), 256, 0, stream>>>(
        h16, W1T + (size_t)l * HID * FF, b1 + (size_t)l * FF, ff16, S, FF, HID);
    gemm_f16_n64_splitk_kernel<<<dim3(HID / 64, S / 128, 2), 256, 0, stream>>>(
        ff16, W2T + (size_t)l * FF * HID, sum16, p1, S, HID, FF);
    ln_ffn2_kernel<<<S, 256, 0, stream>>>(sum16, p1, b2 + (size_t)l * HID,
                                          ln2w + (size_t)l * HID, ln2b + (size_t)l * HID, h16);
  }
  pool_part_kernel<<<64, 256, 0, stream>>>(h16, amask, part);
  cls_head_kernel<<<1, 256, 0, stream>>>(part, amask, clsW, clsb, (float*)d_out);
}

// Round 11
// 2320.877 us; speedup vs baseline: 1.1631x; 1.0047x over previous
//
#include <hip/hip_runtime.h>
#include <cmath>

#define S 4096
#define HID 768
#define NH 12
#define DH 64
#define CHUNK 256
#define NC (S / CHUNK)
#define NG 16
#define FF 3072
#define NLAYER 12
#define QKV3 (3 * HID)
#define NEGV -1e9f

typedef _Float16 f16;
typedef __attribute__((ext_vector_type(2))) _Float16 f16x2;
typedef __attribute__((ext_vector_type(4))) _Float16 f16x4;
typedef __attribute__((ext_vector_type(8))) _Float16 f16x8;
typedef __attribute__((ext_vector_type(4))) float f32x4;

__device__ __forceinline__ void async16(f16* lds, const f16* g) {
  __builtin_amdgcn_global_load_lds((const __attribute__((address_space(1))) unsigned int*)g,
                                   (__attribute__((address_space(3))) unsigned int*)lds,
                                   16, 0, 0);
}

// bijective XCD swizzle for nwg % 8 == 0
__device__ __forceinline__ int xcd_swz(int lin, int nwg) {
  return (lin & 7) * (nwg >> 3) + (lin >> 3);
}

__device__ __forceinline__ float block_reduce_sum(float v, float* red) {
  int t = threadIdx.x;
  red[t] = v; __syncthreads();
  for (int st = 128; st > 0; st >>= 1) {
    if (t < st) red[t] += red[t + st];
    __syncthreads();
  }
  float r = red[0]; __syncthreads();
  return r;
}

// ---------------- gidx / gvalid (matches jax top_k semantics) ----------------
__global__ void gidx_kernel(const int* __restrict__ gmask, int* __restrict__ gidx,
                            float* __restrict__ gvalid) {
  if (threadIdx.x != 0 || blockIdx.x != 0) return;
  int cnt = 0;
  for (int s = 0; s < S && cnt < NG; s++)
    if (gmask[s] > 0) { gidx[cnt] = s; gvalid[cnt] = 1.f; cnt++; }
  for (int s = 0; s < S && cnt < NG; s++)
    if (gmask[s] == 0) { gidx[cnt] = s; gvalid[cnt] = 0.f; cnt++; }
}

// ---------------- embedding + LayerNorm (writes f16 residual stream) ----------------
__global__ __launch_bounds__(256) void embed_ln_kernel(
    const int* __restrict__ ids, const float* __restrict__ tok,
    const float* __restrict__ pos, const float* __restrict__ g,
    const float* __restrict__ b, f16* __restrict__ h16) {
  int s = blockIdx.x, t = threadIdx.x;
  __shared__ float xs[HID];
  __shared__ float red[256];
  const float* tr = tok + (size_t)ids[s] * HID;
  const float* pr = pos + (size_t)s * HID;
  float ls = 0.f;
  for (int i = t; i < HID; i += 256) { float v = tr[i] + pr[i]; xs[i] = v; ls += v; }
  float mu = block_reduce_sum(ls, red) * (1.f / HID);
  float lv = 0.f;
  for (int i = t; i < HID; i += 256) { float d = xs[i] - mu; lv += d * d; }
  float var = block_reduce_sum(lv, red) * (1.f / HID);
  float inv = rsqrtf(var + 1e-5f);
  for (int i = t; i < HID; i += 256)
    h16[(size_t)s * HID + i] = (f16)((xs[i] - mu) * inv * g[i] + b[i]);
}

// ---------------- LayerNorm: sum16 (pre-LN, f16) -> h16, vectorized ----------------
__global__ __launch_bounds__(256) void ln_kernel(
    const f16* __restrict__ sum16, const float* __restrict__ g,
    const float* __restrict__ b, f16* __restrict__ h16) {
  int s = blockIdx.x, t = threadIdx.x;
  __shared__ float red[256];
  float x[4] = {0.f, 0.f, 0.f, 0.f};
  if (t < 192) {
    f16x4 v = *(const f16x4*)&sum16[(size_t)s * HID + t * 4];
#pragma unroll
    for (int e = 0; e < 4; e++) x[e] = (float)v[e];
  }
  float mu = block_reduce_sum(x[0] + x[1] + x[2] + x[3], red) * (1.f / HID);
  float vs = 0.f;
  if (t < 192) {
#pragma unroll
    for (int e = 0; e < 4; e++) { float d = x[e] - mu; vs += d * d; }
  }
  float var = block_reduce_sum(vs, red) * (1.f / HID);
  float inv = rsqrtf(var + 1e-5f);
  if (t < 192) {
    float4 gv = *(const float4*)&g[t * 4];
    float4 bv = *(const float4*)&b[t * 4];
    f16x4 o;
    o[0] = (f16)((x[0] - mu) * inv * gv.x + bv.x);
    o[1] = (f16)((x[1] - mu) * inv * gv.y + bv.y);
    o[2] = (f16)((x[2] - mu) * inv * gv.z + bv.z);
    o[3] = (f16)((x[3] - mu) * inv * gv.w + bv.w);
    *(f16x4*)&h16[(size_t)s * HID + t * 4] = o;
  }
}

// ---- LayerNorm for split-K FFN2: x = p0+p1+bias+resid(h16); LN -> h16, vectorized ----
__global__ __launch_bounds__(256) void ln_ffn2_kernel(
    const f16* __restrict__ p0, const f16* __restrict__ p1,
    const float* __restrict__ bias, const float* __restrict__ g,
    const float* __restrict__ b, f16* __restrict__ h16) {
  int s = blockIdx.x, t = threadIdx.x;
  __shared__ float red[256];
  size_t base = (size_t)s * HID;
  float x[4] = {0.f, 0.f, 0.f, 0.f};
  if (t < 192) {
    f16x4 a = *(const f16x4*)&p0[base + t * 4];
    f16x4 c = *(const f16x4*)&p1[base + t * 4];
    f16x4 r = *(const f16x4*)&h16[base + t * 4];
    float4 bb = *(const float4*)&bias[t * 4];
    x[0] = (float)a[0] + (float)c[0] + bb.x + (float)r[0];
    x[1] = (float)a[1] + (float)c[1] + bb.y + (float)r[1];
    x[2] = (float)a[2] + (float)c[2] + bb.z + (float)r[2];
    x[3] = (float)a[3] + (float)c[3] + bb.w + (float)r[3];
  }
  float mu = block_reduce_sum(x[0] + x[1] + x[2] + x[3], red) * (1.f / HID);
  float vs = 0.f;
  if (t < 192) {
#pragma unroll
    for (int e = 0; e < 4; e++) { float d = x[e] - mu; vs += d * d; }
  }
  float var = block_reduce_sum(vs, red) * (1.f / HID);
  float inv = rsqrtf(var + 1e-5f);
  if (t < 192) {
    float4 gv = *(const float4*)&g[t * 4];
    float4 bv = *(const float4*)&b[t * 4];
    f16x4 o;
    o[0] = (f16)((x[0] - mu) * inv * gv.x + bv.x);
    o[1] = (f16)((x[1] - mu) * inv * gv.y + bv.y);
    o[2] = (f16)((x[2] - mu) * inv * gv.z + bv.z);
    o[3] = (f16)((x[3] - mu) * inv * gv.w + bv.w);
    *(f16x4*)&h16[base + t * 4] = o;
  }
}

// ------ weight transpose + f16 convert, ALL layers: W[l][K][N] f32 -> WT[l][N][K] f16
__global__ __launch_bounds__(256) void wt_kernel(const float* __restrict__ W,
                                                 f16* __restrict__ WT, int K, int N) {
  size_t lo = (size_t)blockIdx.z * K * N;
  const float* Wl = W + lo;
  f16* WTl = WT + lo;
  __shared__ float tile[32][33];
  int k0 = blockIdx.y * 32, n0 = blockIdx.x * 32;
  int t = threadIdx.x;
  int r = t >> 3, c = (t & 7) * 4;
  float4 v = *(const float4*)&Wl[(size_t)(k0 + r) * N + n0 + c];
  tile[r][c] = v.x; tile[r][c + 1] = v.y; tile[r][c + 2] = v.z; tile[r][c + 3] = v.w;
  __syncthreads();
  int n = t >> 3, kq = (t & 7) * 4;
  f16x4 o = {(f16)tile[kq][n], (f16)tile[kq + 1][n], (f16)tile[kq + 2][n], (f16)tile[kq + 3][n]};
  *(f16x4*)&WTl[(size_t)(n0 + n) * K + k0 + kq] = o;
}

// ---- fp16 MFMA GEMM 128x128, single-buffer 2-barrier + coalesced LDS epilogue ----
#define GBK 64

template <bool GELU>
__global__ __launch_bounds__(256) void gemm_f16_kernel(
    const f16* __restrict__ A, const f16* __restrict__ BT,
    const float* __restrict__ bias, f16* __restrict__ Cout, int M, int N, int K) {
  __shared__ f16 smem[17408];  // loop: As(8192)|Bs(8192); epilogue: C[128][136]
  f16* As = smem;
  f16* Bs = smem + 8192;
  int t = threadIdx.x, lane = t & 63, wave = t >> 6;
  int wr = wave >> 1, wc = wave & 1;
  int gx = gridDim.x;
  int nl = xcd_swz(blockIdx.y * gx + blockIdx.x, gx * gridDim.y);
  int bx = nl % gx, by = nl / gx;

  f32x4 acc[4][4];
#pragma unroll
  for (int mi = 0; mi < 4; mi++)
#pragma unroll
    for (int ni = 0; ni < 4; ni++) acc[mi][ni] = (f32x4){0.f, 0.f, 0.f, 0.f};

  const f16* Ablk = A + (size_t)(by * 128) * K;
  const f16* Bblk = BT + (size_t)(bx * 128) * K;
  int rl = lane >> 3;
  int lc = (lane & 7) ^ rl;

  for (int k0 = 0; k0 < K; k0 += GBK) {
#pragma unroll
    for (int ii = 0; ii < 4; ii++) {
      int i = wave * 4 + ii;
      int r = i * 8 + rl;
      async16(&As[i * 512], Ablk + (size_t)r * K + k0 + lc * 8);
      async16(&Bs[i * 512], Bblk + (size_t)r * K + k0 + lc * 8);
    }
    __syncthreads();
#pragma unroll
    for (int kc = 0; kc < 2; kc++) {
      f16x8 af[4], bf[4];
#pragma unroll
      for (int mi = 0; mi < 4; mi++) {
        int row = wr * 64 + mi * 16 + (lane & 15);
        int pc = (kc * 4 + (lane >> 4)) ^ (row & 7);
        af[mi] = *(const f16x8*)&As[row * 64 + pc * 8];
      }
#pragma unroll
      for (int ni = 0; ni < 4; ni++) {
        int row = wc * 64 + ni * 16 + (lane & 15);
        int pc = (kc * 4 + (lane >> 4)) ^ (row & 7);
        bf[ni] = *(const f16x8*)&Bs[row * 64 + pc * 8];
      }
#pragma unroll
      for (int mi = 0; mi < 4; mi++)
#pragma unroll
        for (int ni = 0; ni < 4; ni++)
          acc[mi][ni] = __builtin_amdgcn_mfma_f32_16x16x32_f16(af[mi], bf[ni], acc[mi][ni], 0, 0, 0);
    }
    __syncthreads();
  }

  // epilogue: stage f16 C tile in LDS, read back coalesced
  f16* Cs = smem;  // [128][136]
  int rloc = wr * 64 + (lane >> 4) * 4;
  int cloc = wc * 64 + (lane & 15);
#pragma unroll
  for (int mi = 0; mi < 4; mi++) {
#pragma unroll
    for (int ni = 0; ni < 4; ni++) {
      int col = cloc + ni * 16;
      float bs = bias[bx * 128 + col];
#pragma unroll
      for (int j = 0; j < 4; j++) {
        float x = acc[mi][ni][j] + bs;
        if (GELU) x = 0.5f * x * (1.f + erff(x * 0.70710678118654752f));
        Cs[(rloc + mi * 16 + j) * 136 + col] = (f16)x;
      }
    }
  }
  __syncthreads();
  size_t Cb = (size_t)(by * 128) * N + bx * 128;
#pragma unroll
  for (int p = 0; p < 8; p++) {
    int idx = p * 256 + t;
    int row = idx >> 4, ch = idx & 15;
    f16x8 v = *(const f16x8*)&Cs[row * 136 + ch * 8];
    *(f16x8*)&Cout[Cb + (size_t)row * N + ch * 8] = v;
  }
}

// ---- fp16 MFMA GEMM 128x64 (N=768 outputs), fused residual, coalesced epilogue ----
template <bool RESID>
__global__ __launch_bounds__(256) void gemm_f16_n64_kernel(
    const f16* __restrict__ A, const f16* __restrict__ BT,
    const float* __restrict__ bias, const f16* __restrict__ resid,
    f16* __restrict__ Cout, int M, int N, int K) {
  __shared__ f16 smem[12288];  // loop: As(8192)|Bs(4096); epilogue: C[128][72]
  f16* As = smem;
  f16* Bs = smem + 8192;
  int t = threadIdx.x, lane = t & 63, wave = t >> 6;
  int wr = wave >> 1, wc = wave & 1;
  int gx = gridDim.x;
  int nl = xcd_swz(blockIdx.y * gx + blockIdx.x, gx * gridDim.y);
  int bx = nl % gx, by = nl / gx;

  f32x4 acc[4][2];
#pragma unroll
  for (int mi = 0; mi < 4; mi++)
#pragma unroll
    for (int ni = 0; ni < 2; ni++) acc[mi][ni] = (f32x4){0.f, 0.f, 0.f, 0.f};

  const f16* Ablk = A + (size_t)(by * 128) * K;
  const f16* Bblk = BT + (size_t)(bx * 64) * K;
  int rl = lane >> 3;
  int lc = (lane & 7) ^ rl;

  for (int k0 = 0; k0 < K; k0 += GBK) {
#pragma unroll
    for (int ii = 0; ii < 4; ii++) {
      int i = wave * 4 + ii;
      int r = i * 8 + rl;
      async16(&As[i * 512], Ablk + (size_t)r * K + k0 + lc * 8);
    }
#pragma unroll
    for (int ii = 0; ii < 2; ii++) {
      int i = wave * 2 + ii;
      int r = i * 8 + rl;
      async16(&Bs[i * 512], Bblk + (size_t)r * K + k0 + lc * 8);
    }
    __syncthreads();
#pragma unroll
    for (int kc = 0; kc < 2; kc++) {
      f16x8 af[4], bf[2];
#pragma unroll
      for (int mi = 0; mi < 4; mi++) {
        int row = wr * 64 + mi * 16 + (lane & 15);
        int pc = (kc * 4 + (lane >> 4)) ^ (row & 7);
        af[mi] = *(const f16x8*)&As[row * 64 + pc * 8];
      }
#pragma unroll
      for (int ni = 0; ni < 2; ni++) {
        int row = wc * 32 + ni * 16 + (lane & 15);
        int pc = (kc * 4 + (lane >> 4)) ^ (row & 7);
        bf[ni] = *(const f16x8*)&Bs[row * 64 + pc * 8];
      }
#pragma unroll
      for (int mi = 0; mi < 4; mi++)
#pragma unroll
        for (int ni = 0; ni < 2; ni++)
          acc[mi][ni] = __builtin_amdgcn_mfma_f32_16x16x32_f16(af[mi], bf[ni], acc[mi][ni], 0, 0, 0);
    }
    __syncthreads();
  }

  f16* Cs = smem;  // [128][72]
  int rloc = wr * 64 + (lane >> 4) * 4;
  int cloc = wc * 32 + (lane & 15);
#pragma unroll
  for (int mi = 0; mi < 4; mi++) {
#pragma unroll
    for (int ni = 0; ni < 2; ni++) {
      int col = cloc + ni * 16;
      float bs = bias[bx * 64 + col];
#pragma unroll
      for (int j = 0; j < 4; j++)
        Cs[(rloc + mi * 16 + j) * 72 + col] = (f16)(acc[mi][ni][j] + bs);
    }
  }
  __syncthreads();
  size_t Cb = (size_t)(by * 128) * N + bx * 64;
#pragma unroll
  for (int p = 0; p < 4; p++) {
    int idx = p * 256 + t;
    int row = idx >> 3, ch = idx & 7;
    f16x8 v = *(const f16x8*)&Cs[row * 72 + ch * 8];
    if (RESID) {
      f16x8 r = *(const f16x8*)&resid[Cb + (size_t)row * N + ch * 8];
#pragma unroll
      for (int e = 0; e < 8; e++) v[e] = (f16)((float)v[e] + (float)r[e]);
    }
    *(f16x8*)&Cout[Cb + (size_t)row * N + ch * 8] = v;
  }
}

// ---- fp16 MFMA GEMM 128x64 split-K (z=0/1): raw f16 partials, coalesced epilogue ----
__global__ __launch_bounds__(256) void gemm_f16_n64_splitk_kernel(
    const f16* __restrict__ A, const f16* __restrict__ BT,
    f16* __restrict__ p0, f16* __restrict__ p1, int M, int N, int K) {
  __shared__ f16 smem[12288];
  f16* As = smem;
  f16* Bs = smem + 8192;
  int t = threadIdx.x, lane = t & 63, wave = t >> 6;
  int wr = wave >> 1, wc = wave & 1;
  int gx = gridDim.x;
  int nl = xcd_swz(blockIdx.y * gx + blockIdx.x, gx * gridDim.y);
  int bx = nl % gx, by = nl / gx;
  int kz = blockIdx.z;
  int KH = K >> 1;
  f16* pout = kz ? p1 : p0;

  f32x4 acc[4][2];
#pragma unroll
  for (int mi = 0; mi < 4; mi++)
#pragma unroll
    for (int ni = 0; ni < 2; ni++) acc[mi][ni] = (f32x4){0.f, 0.f, 0.f, 0.f};

  const f16* Ablk = A + (size_t)(by * 128) * K + (size_t)kz * KH;
  const f16* Bblk = BT + (size_t)(bx * 64) * K + (size_t)kz * KH;
  int rl = lane >> 3;
  int lc = (lane & 7) ^ rl;

  for (int k0 = 0; k0 < KH; k0 += GBK) {
#pragma unroll
    for (int ii = 0; ii < 4; ii++) {
      int i = wave * 4 + ii;
      int r = i * 8 + rl;
      async16(&As[i * 512], Ablk + (size_t)r * K + k0 + lc * 8);
    }
#pragma unroll
    for (int ii = 0; ii < 2; ii++) {
      int i = wave * 2 + ii;
      int r = i * 8 + rl;
      async16(&Bs[i * 512], Bblk + (size_t)r * K + k0 + lc * 8);
    }
    __syncthreads();
#pragma unroll
    for (int kc = 0; kc < 2; kc++) {
      f16x8 af[4], bf[2];
#pragma unroll
      for (int mi = 0; mi < 4; mi++) {
        int row = wr * 64 + mi * 16 + (lane & 15);
        int pc = (kc * 4 + (lane >> 4)) ^ (row & 7);
        af[mi] = *(const f16x8*)&As[row * 64 + pc * 8];
      }
#pragma unroll
      for (int ni = 0; ni < 2; ni++) {
        int row = wc * 32 + ni * 16 + (lane & 15);
        int pc = (kc * 4 + (lane >> 4)) ^ (row & 7);
        bf[ni] = *(const f16x8*)&Bs[row * 64 + pc * 8];
      }
#pragma unroll
      for (int mi = 0; mi < 4; mi++)
#pragma unroll
        for (int ni = 0; ni < 2; ni++)
          acc[mi][ni] = __builtin_amdgcn_mfma_f32_16x16x32_f16(af[mi], bf[ni], acc[mi][ni], 0, 0, 0);
    }
    __syncthreads();
  }

  f16* Cs = smem;  // [128][72]
  int rloc = wr * 64 + (lane >> 4) * 4;
  int cloc = wc * 32 + (lane & 15);
#pragma unroll
  for (int mi = 0; mi < 4; mi++)
#pragma unroll
    for (int ni = 0; ni < 2; ni++)
#pragma unroll
      for (int j = 0; j < 4; j++)
        Cs[(rloc + mi * 16 + j) * 72 + cloc + ni * 16] = (f16)acc[mi][ni][j];
  __syncthreads();
  size_t Cb = (size_t)(by * 128) * N + bx * 64;
#pragma unroll
  for (int p = 0; p < 4; p++) {
    int idx = p * 256 + t;
    int row = idx >> 3, ch = idx & 7;
    f16x8 v = *(const f16x8*)&Cs[row * 72 + ch * 8];
    *(f16x8*)&pout[Cb + (size_t)row * N + ch * 8] = v;
  }
}

// ---------------- MFMA local windowed attention, T14 async-stage prefetch ----------------
#define ROWP 72  // padded LDS row: 64 halves + 8 pad (144B)

__device__ __forceinline__ void pf_load(
    const f16* __restrict__ qkv, const int* __restrict__ gidx, const float* gvs,
    int h, int q0, int kt, int t,
    f16x8& pk0, f16x8& pk1, f16x8& pva, f16x8& pvb) {
  int jb = q0 - 256 + kt * 64;
  bool isG = (kt == 9);
  pk0 = (f16x8){}; pk1 = (f16x8){}; pva = (f16x8){}; pvb = (f16x8){};
  int kr = t >> 2, c2 = (t & 3) * 2;
  bool kok_;
  int jk;
  if (isG) { kok_ = (kr < NG) && (gvs[kr] > 0.f); jk = kok_ ? gidx[kr] : 0; }
  else { kok_ = true; jk = jb + kr; }
  if (kok_) {
    const f16* kp = qkv + (size_t)jk * QKV3 + HID + h * DH + c2 * 8;
    pk0 = *(const f16x8*)kp;
    pk1 = *(const f16x8*)(kp + 8);
  }
  int k2 = (t & 31) * 2, dq = (t >> 5) * 8;
  bool o0, o1;
  int j0, j1;
  if (isG) {
    o0 = (k2 < NG) && (gvs[k2] > 0.f); j0 = o0 ? gidx[k2] : 0;
    o1 = (k2 + 1 < NG) && (gvs[k2 + 1] > 0.f); j1 = o1 ? gidx[k2 + 1] : 0;
  } else { o0 = o1 = true; j0 = jb + k2; j1 = jb + k2 + 1; }
  if (o0) pva = *(const f16x8*)(qkv + (size_t)j0 * QKV3 + 2 * HID + h * DH + dq);
  if (o1) pvb = *(const f16x8*)(qkv + (size_t)j1 * QKV3 + 2 * HID + h * DH + dq);
}

__global__ __launch_bounds__(256) void local_attn_mfma_kernel(
    const f16* __restrict__ qkv, const int* __restrict__ amask,
    const int* __restrict__ gmask, const int* __restrict__ gidx,
    const float* __restrict__ gvalid, f16* __restrict__ outp) {
  int nl = xcd_swz(blockIdx.x, NH * 64);
  int h = nl >> 6;
  int qb = nl & 63;
  int q0 = qb * 64;
  int t = threadIdx.x, lane = t & 63, w = t >> 6;
  int g4 = lane >> 4, l15 = lane & 15;

  __shared__ f16 Qs[64 * ROWP];
  __shared__ f16 Kt[64 * ROWP];
  __shared__ f16 Vt[64 * ROWP];
  __shared__ f16 Pb[4 * 16 * ROWP];
  __shared__ unsigned kokLo, kokHi;
  __shared__ float gvs[NG];

  {  // stage Q (scaled by 1/8)
    int r = t >> 2, c2 = (t & 3) * 2;
    const f16* qr = qkv + (size_t)(q0 + r) * QKV3 + h * DH + c2 * 8;
    f16x8 v0 = *(const f16x8*)qr;
    f16x8 v1 = *(const f16x8*)(qr + 8);
#pragma unroll
    for (int e = 0; e < 8; e++) { v0[e] = v0[e] * (f16)0.125f; v1[e] = v1[e] * (f16)0.125f; }
    *(f16x8*)&Qs[r * ROWP + c2 * 8] = v0;
    *(f16x8*)&Qs[r * ROWP + c2 * 8 + 8] = v1;
    if (t < NG) gvs[t] = gvalid[t];
  }
  __syncthreads();

  int qrow = w * 16 + l15;
  f16x8 qf0 = *(const f16x8*)&Qs[qrow * ROWP + g4 * 8];
  f16x8 qf1 = *(const f16x8*)&Qs[qrow * ROWP + 32 + g4 * 8];

  float mb = -50000.f, lp = 0.f;
  f32x4 oacc[4];
#pragma unroll
  for (int sd = 0; sd < 4; sd++) oacc[sd] = (f32x4){0.f, 0.f, 0.f, 0.f};

  f16* Pw = &Pb[w * 16 * ROWP];

  int kt_lo = q0 >= 256 ? 0 : (256 - q0) >> 6;
  int kt_hi = (4288 - q0) >> 6;
  if (kt_hi > 8) kt_hi = 8;
  int ntile = kt_hi - kt_lo + 2;

  f16x8 pk0, pk1, pva, pvb;
  pf_load(qkv, gidx, gvs, h, q0, kt_lo, t, pk0, pk1, pva, pvb);

  for (int it = 0; it < ntile; it++) {
    int kt = (it < ntile - 1) ? kt_lo + it : 9;
    int jb = q0 - 256 + kt * 64;
    bool isG = (kt == 9);
    __syncthreads();
    {  // write prefetched K [k][d]
      int kr = t >> 2, c2 = (t & 3) * 2;
      *(f16x8*)&Kt[kr * ROWP + c2 * 8] = pk0;
      *(f16x8*)&Kt[kr * ROWP + c2 * 8 + 8] = pk1;
    }
    {  // write prefetched V transposed [d][k]
      int k2 = (t & 31) * 2, dq = (t >> 5) * 8;
#pragma unroll
      for (int e = 0; e < 8; e++) {
        f16x2 pr = {pva[e], pvb[e]};
        *(f16x2*)&Vt[(dq + e) * ROWP + k2] = pr;
      }
    }
    if (w == 0) {  // key-ok bitmask
      int k = lane;
      bool ok;
      if (isG) ok = (k < NG && gvs[k] > 0.f);
      else {
        int j = jb + k;
        ok = (amask[j] != 0) && (gmask[j] == 0);
      }
      unsigned long long m = __ballot(ok);
      if (lane == 0) { kokLo = (unsigned)m; kokHi = (unsigned)(m >> 32); }
    }
    if (it + 1 < ntile) {  // T14: issue next tile's loads
      int ktn = (it + 1 < ntile - 1) ? kt_lo + it + 1 : 9;
      pf_load(qkv, gidx, gvs, h, q0, ktn, t, pk0, pk1, pva, pvb);
    }
    __syncthreads();

    unsigned long long kok = ((unsigned long long)kokHi << 32) | (unsigned long long)kokLo;

    f32x4 sv[4];
    __builtin_amdgcn_s_setprio(1);
#pragma unroll
    for (int s4 = 0; s4 < 4; s4++) {
      int krow = s4 * 16 + l15;
      f16x8 ka0 = *(const f16x8*)&Kt[krow * ROWP + g4 * 8];
      f16x8 ka1 = *(const f16x8*)&Kt[krow * ROWP + 32 + g4 * 8];
      f32x4 a = {0.f, 0.f, 0.f, 0.f};
      a = __builtin_amdgcn_mfma_f32_16x16x32_f16(ka0, qf0, a, 0, 0, 0);
      a = __builtin_amdgcn_mfma_f32_16x16x32_f16(ka1, qf1, a, 0, 0, 0);
      sv[s4] = a;
    }
    __builtin_amdgcn_s_setprio(0);
    int ql = w * 16 + l15;
#pragma unroll
    for (int s4 = 0; s4 < 4; s4++)
#pragma unroll
      for (int r = 0; r < 4; r++) {
        int kl = s4 * 16 + g4 * 4 + r;
        bool ok = (kok >> kl) & 1ull;
        if (kt == 0) ok = ok && (kl >= ql);
        else if (kt == 8) ok = ok && (kl <= ql);
        sv[s4][r] = ok ? sv[s4][r] : -1e30f;
      }
    float mt = -1e30f;
#pragma unroll
    for (int s4 = 0; s4 < 4; s4++)
#pragma unroll
      for (int r = 0; r < 4; r++) mt = fmaxf(mt, sv[s4][r]);
    mt = fmaxf(mt, __shfl_xor(mt, 16));
    mt = fmaxf(mt, __shfl_xor(mt, 32));
    float mn = fmaxf(mb, mt);
    float corr = __expf(mb - mn);
    mb = mn;
    lp *= corr;
#pragma unroll
    for (int sd = 0; sd < 4; sd++)
#pragma unroll
      for (int r = 0; r < 4; r++) oacc[sd][r] *= corr;
#pragma unroll
    for (int s4 = 0; s4 < 4; s4++) {
#pragma unroll
      for (int rp = 0; rp < 2; rp++) {
        float p0 = __expf(sv[s4][rp * 2] - mn);
        float p1 = __expf(sv[s4][rp * 2 + 1] - mn);
        f16 h0 = (f16)p0, h1 = (f16)p1;
        lp += (float)h0 + (float)h1;
        int kl = s4 * 16 + g4 * 4 + rp * 2;
        f16x2 pr = {h0, h1};
        *(f16x2*)&Pw[l15 * ROWP + kl] = pr;
      }
    }
    f16x8 pf0 = *(const f16x8*)&Pw[l15 * ROWP + g4 * 8];
    f16x8 pf1 = *(const f16x8*)&Pw[l15 * ROWP + 32 + g4 * 8];
    __builtin_amdgcn_s_setprio(1);
#pragma unroll
    for (int sd = 0; sd < 4; sd++) {
      int drow = sd * 16 + l15;
      f16x8 va0 = *(const f16x8*)&Vt[drow * ROWP + g4 * 8];
      f16x8 va1 = *(const f16x8*)&Vt[drow * ROWP + 32 + g4 * 8];
      oacc[sd] = __builtin_amdgcn_mfma_f32_16x16x32_f16(va0, pf0, oacc[sd], 0, 0, 0);
      oacc[sd] = __builtin_amdgcn_mfma_f32_16x16x32_f16(va1, pf1, oacc[sd], 0, 0, 0);
    }
    __builtin_amdgcn_s_setprio(0);
  }

  float lt = lp + __shfl_xor(lp, 16);
  lt = lt + __shfl_xor(lt, 32);
  float inv = (lt > 0.f) ? 1.f / lt : 0.f;
  int qg = q0 + w * 16 + l15;
  f16* orow = outp + (size_t)qg * HID + h * DH;
#pragma unroll
  for (int sd = 0; sd < 4; sd++)
#pragma unroll
    for (int r = 0; r < 4; r++)
      orow[sd * 16 + g4 * 4 + r] = (f16)(oacc[sd][r] * inv);
}

// ============ global-token attention, split-K pipeline ============
__global__ __launch_bounds__(256) void gscore_kernel(
    const f16* __restrict__ qkv, const int* __restrict__ amask,
    const int* __restrict__ gidx, float* __restrict__ Sg, float2* __restrict__ cstat) {
  int h = blockIdx.x >> 4, jc = blockIdx.x & 15;
  int t = threadIdx.x, lane = t & 63, w = t >> 6;
  __shared__ f16 Qs[NG][DH];
  __shared__ float wred[4][NG];
  __shared__ float cmaxs[NG];
  if (t < 128) {
    int g = t >> 3, c = (t & 7) * 8;
    const f16* qr = qkv + (size_t)gidx[g] * QKV3 + h * DH + c;
    *(f16x8*)&Qs[g][c] = *(const f16x8*)qr;
  }
  __syncthreads();
  int j = jc * 256 + t;
  const f16x8* kr = (const f16x8*)(qkv + (size_t)j * QKV3 + HID + h * DH);
  f16x8 kv[8];
#pragma unroll
  for (int c = 0; c < 8; c++) kv[c] = kr[c];
  bool ok = amask[j] != 0;
  float sg[NG];
#pragma unroll 4
  for (int g = 0; g < NG; g++) {
    float s = 0.f;
#pragma unroll
    for (int c = 0; c < 8; c++) {
      f16x8 qv = *(const f16x8*)&Qs[g][c * 8];
#pragma unroll
      for (int e = 0; e < 8; e++) s += (float)qv[e] * (float)kv[c][e];
    }
    sg[g] = ok ? s * 0.125f : NEGV;
    Sg[(size_t)(h * NG + g) * S + j] = sg[g];
  }
#pragma unroll
  for (int g = 0; g < NG; g++) {
    float m = sg[g];
#pragma unroll
    for (int st = 1; st < 64; st <<= 1) m = fmaxf(m, __shfl_xor(m, st));
    if (lane == 0) wred[w][g] = m;
  }
  __syncthreads();
  if (t < NG)
    cmaxs[t] = fmaxf(fmaxf(wred[0][t], wred[1][t]), fmaxf(wred[2][t], wred[3][t]));
  __syncthreads();
#pragma unroll
  for (int g = 0; g < NG; g++) {
    float p = __expf(sg[g] - cmaxs[g]);
#pragma unroll
    for (int st = 1; st < 64; st <<= 1) p += __shfl_xor(p, st);
    if (lane == 0) wred[w][g] = p;
  }
  __syncthreads();
  if (t < NG) {
    float s4 = wred[0][t] + wred[1][t] + wred[2][t] + wred[3][t];
    cstat[((size_t)(h * NG + t)) * 16 + jc] = make_float2(cmaxs[t], s4);
  }
}

__global__ __launch_bounds__(256) void gpv_kernel(
    const f16* __restrict__ qkv, const float* __restrict__ Sg,
    const float2* __restrict__ cstat, float* __restrict__ part) {
  int h = blockIdx.x >> 4, jc = blockIdx.x & 15;
  int jb = jc * 256;
  int t = threadIdx.x;
  __shared__ float Ps[NG][256];
  __shared__ f16 Vs[256][DH];
  __shared__ float ms[NG], dinv[NG];
  if (t < NG) {
    const float2* cs = &cstat[((size_t)(h * NG + t)) * 16];
    float m = -1e30f;
#pragma unroll
    for (int c = 0; c < 16; c++) m = fmaxf(m, cs[c].x);
    float den = 0.f;
#pragma unroll
    for (int c = 0; c < 16; c++) den += cs[c].y * __expf(cs[c].x - m);
    ms[t] = m;
    dinv[t] = den > 0.f ? 1.f / den : 0.f;
  }
  __syncthreads();
#pragma unroll
  for (int g = 0; g < NG; g++)
    Ps[g][t] = __expf(Sg[(size_t)(h * NG + g) * S + jb + t] - ms[g]) * dinv[g];
  {
    int r = t >> 3, c = (t & 7) * 8;
#pragma unroll
    for (int pp = 0; pp < 8; pp++) {
      int row = pp * 32 + r;
      const f16* vr = qkv + (size_t)(jb + row) * QKV3 + 2 * HID + h * DH + c;
      *(f16x8*)&Vs[row][c] = *(const f16x8*)vr;
    }
  }
  __syncthreads();
  int d = t & 63, g4 = t >> 6;
  float o0 = 0.f, o1 = 0.f, o2 = 0.f, o3 = 0.f;
#pragma unroll 8
  for (int j = 0; j < 256; j++) {
    float v = (float)Vs[j][d];
    o0 += Ps[g4][j] * v;
    o1 += Ps[g4 + 4][j] * v;
    o2 += Ps[g4 + 8][j] * v;
    o3 += Ps[g4 + 12][j] * v;
  }
  size_t base = ((size_t)h * NG) * 16 * 64;
  part[base + ((size_t)(g4) * 16 + jc) * 64 + d] = o0;
  part[base + ((size_t)(g4 + 4) * 16 + jc) * 64 + d] = o1;
  part[base + ((size_t)(g4 + 8) * 16 + jc) * 64 + d] = o2;
  part[base + ((size_t)(g4 + 12) * 16 + jc) * 64 + d] = o3;
}

__global__ __launch_bounds__(64) void gout_kernel(
    const float* __restrict__ part, const int* __restrict__ gidx,
    const float* __restrict__ gvalid, f16* __restrict__ attn16) {
  int h = blockIdx.x >> 4, g = blockIdx.x & 15;
  if (gvalid[g] <= 0.f) return;
  int d = threadIdx.x;
  const float* pr = part + (((size_t)(h * NG + g)) * 16) * 64 + d;
  float s = 0.f;
#pragma unroll
  for (int jc = 0; jc < 16; jc++) s += pr[jc * 64];
  attn16[(size_t)gidx[g] * HID + h * DH + d] = (f16)s;
}

// ---------------- masked mean pool (partials) + classifier head ----------------
__global__ __launch_bounds__(256) void pool_part_kernel(
    const f16* __restrict__ h, const int* __restrict__ amask, float* __restrict__ part) {
  int b = blockIdx.x, t = threadIdx.x;
  if (t >= 192) return;
  float a[4] = {0.f, 0.f, 0.f, 0.f};
  for (int r = 0; r < 64; r++) {
    int s = b * 64 + r;
    float w = (float)amask[s];
    f16x4 v = *(const f16x4*)&h[(size_t)s * HID + t * 4];
#pragma unroll
    for (int e = 0; e < 4; e++) a[e] += (float)v[e] * w;
  }
  float4 o = {a[0], a[1], a[2], a[3]};
  *(float4*)&part[(size_t)b * HID + t * 4] = o;
}

__global__ __launch_bounds__(256) void cls_head_kernel(
    const float* __restrict__ part, const int* __restrict__ amask,
    const float* __restrict__ clsW, const float* __restrict__ clsb,
    float* __restrict__ out) {
  __shared__ float pooled[HID];
  __shared__ float red[256];
  int t = threadIdx.x;
  for (int i = t; i < HID; i += 256) {
    float s = 0.f;
    for (int b2 = 0; b2 < 64; b2++) s += part[(size_t)b2 * HID + i];
    pooled[i] = s;
  }
  float c = 0.f;
  for (int s2 = t; s2 < S; s2 += 256) c += (float)amask[s2];
  float cnt = block_reduce_sum(c, red);
  float p0 = 0.f, p1 = 0.f;
  for (int i = t; i < HID; i += 256) {
    float pv = pooled[i] / cnt;
    p0 += pv * clsW[i * 2];
    p1 += pv * clsW[i * 2 + 1];
  }
  float s0 = block_reduce_sum(p0, red);
  float s1 = block_reduce_sum(p1, red);
  if (t == 0) { out[0] = s0 + clsb[0]; out[1] = s1 + clsb[1]; }
}

// ---------------- launch ----------------
extern "C" void kernel_launch(void* const* d_in, const int* in_sizes, int n_in,
                              void* d_out, int out_size, void* d_ws, size_t ws_size,
                              hipStream_t stream) {
  const int* ids = (const int*)d_in[0];
  const int* amask = (const int*)d_in[1];
  const int* gmask = (const int*)d_in[2];
  const float* tok = (const float*)d_in[3];
  const float* pos = (const float*)d_in[4];
  const float* elnw = (const float*)d_in[5];
  const float* elnb = (const float*)d_in[6];
  const float* Wqkv = (const float*)d_in[7];
  const float* bqkv = (const float*)d_in[8];
  const float* Wo = (const float*)d_in[9];
  const float* bo = (const float*)d_in[10];
  const float* ln1w = (const float*)d_in[11];
  const float* ln1b = (const float*)d_in[12];
  const float* W1 = (const float*)d_in[13];
  const float* b1 = (const float*)d_in[14];
  const float* W2 = (const float*)d_in[15];
  const float* b2 = (const float*)d_in[16];
  const float* ln2w = (const float*)d_in[17];
  const float* ln2b = (const float*)d_in[18];
  const float* clsW = (const float*)d_in[19];
  const float* clsb = (const float*)d_in[20];

  char* w8 = (char*)d_ws;
  size_t o = 0;
  f16* h16 = (f16*)(w8 + o); o += (size_t)S * HID * 2;
  f16* qkv16 = (f16*)(w8 + o); o += (size_t)S * QKV3 * 2;
  f16* attn16 = (f16*)(w8 + o); o += (size_t)S * HID * 2;
  f16* ff16 = (f16*)(w8 + o); o += (size_t)S * FF * 2;
  f16* sum16 = (f16*)(w8 + o); o += (size_t)S * HID * 2;  // split-K p0
  f16* p1 = (f16*)(w8 + o); o += (size_t)S * HID * 2;     // split-K p1
  float* part = (float*)(w8 + o); o += (size_t)64 * HID * 4;
  int* gidx = (int*)(w8 + o); o += 64;
  float* gvalid = (float*)(w8 + o); o += 64;
  f16* WqkvT = (f16*)(w8 + o); o += (size_t)NLAYER * HID * QKV3 * 2;
  f16* WoT = (f16*)(w8 + o); o += (size_t)NLAYER * HID * HID * 2;
  f16* W1T = (f16*)(w8 + o); o += (size_t)NLAYER * HID * FF * 2;
  f16* W2T = (f16*)(w8 + o); o += (size_t)NLAYER * FF * HID * 2;
  float* Sg = (float*)(w8 + o); o += (size_t)NH * NG * S * 4;
  float2* cstat = (float2*)(w8 + o); o += (size_t)NH * NG * 16 * 8;
  float* gpart = (float*)(w8 + o); o += (size_t)NH * NG * 16 * 64 * 4;

  gidx_kernel<<<1, 64, 0, stream>>>(gmask, gidx, gvalid);
  embed_ln_kernel<<<S, 256, 0, stream>>>(ids, tok, pos, elnw, elnb, h16);
  wt_kernel<<<dim3(QKV3 / 32, HID / 32, NLAYER), 256, 0, stream>>>(Wqkv, WqkvT, HID, QKV3);
  wt_kernel<<<dim3(HID / 32, HID / 32, NLAYER), 256, 0, stream>>>(Wo, WoT, HID, HID);
  wt_kernel<<<dim3(FF / 32, HID / 32, NLAYER), 256, 0, stream>>>(W1, W1T, HID, FF);
  wt_kernel<<<dim3(HID / 32, FF / 32, NLAYER), 256, 0, stream>>>(W2, W2T, FF, HID);

  for (int l = 0; l < NLAYER; l++) {
    gemm_f16_kernel<false><<<dim3(QKV3 / 128, S / 128), 256, 0, stream>>>(
        h16, WqkvT + (size_t)l * HID * QKV3, bqkv + (size_t)l * QKV3, qkv16, S, QKV3, HID);
    local_attn_mfma_kernel<<<NH * 64, 256, 0, stream>>>(
        qkv16, amask, gmask, gidx, gvalid, attn16);
    gscore_kernel<<<NH * 16, 256, 0, stream>>>(qkv16, amask, gidx, Sg, cstat);
    gpv_kernel<<<NH * 16, 256, 0, stream>>>(qkv16, Sg, cstat, gpart);
    gout_kernel<<<NH * NG, 64, 0, stream>>>(gpart, gidx, gvalid, attn16);
    gemm_f16_n64_kernel<true><<<dim3(HID / 64, S / 128), 256, 0, stream>>>(
        attn16, WoT + (size_t)l * HID * HID, bo + (size_t)l * HID, h16, sum16, S, HID, HID);
    ln_kernel<<<S, 256, 0, stream>>>(sum16, ln1w + (size_t)l * HID, ln1b + (size_t)l * HID, h16);
    gemm_f16_kernel<true><<<dim3(FF / 128, S / 128), 256, 0, stream>>>(
        h16, W1T + (size_t)l * HID * FF, b1 + (size_t)l * FF, ff16, S, FF, HID);
    gemm_f16_n64_splitk_kernel<<<dim3(HID / 64, S / 128, 2), 256, 0, stream>>>(
        ff16, W2T + (size_t)l * FF * HID, sum16, p1, S, HID, FF);
    ln_ffn2_kernel<<<S, 256, 0, stream>>>(sum16, p1, b2 + (size_t)l * HID,
                                          ln2w + (size_t)l * HID, ln2b + (size_t)l * HID, h16);
  }
  pool_part_kernel<<<64, 256, 0, stream>>>(h16, amask, part);
  cls_head_kernel<<<1, 256, 0, stream>>>(part, amask, clsW, clsb, (float*)d_out);
}